// Round 11
// baseline (440.509 us; speedup 1.0000x reference)
//
#include <hip/hip_runtime.h>
#include <cstdint>
#include <cstddef>

#define HIDDEN 3584
#define NH 28
#define NKV 4
#define HD 128
#define SEQ 2048
#define NB 2
#define REP (NH / NKV)   // 7
#define QSTR 4608        // fused qkv row stride (3584 + 512 + 512)
#define KOFF 3584
#define VOFF 4096

typedef unsigned short u16;
typedef unsigned int u32;
typedef __bf16 bf16x8 __attribute__((ext_vector_type(8)));
typedef __bf16 bf16x2 __attribute__((ext_vector_type(2)));
typedef float f32x4 __attribute__((ext_vector_type(4)));
typedef u16 u16x8 __attribute__((ext_vector_type(8)));
typedef u16 u16x16 __attribute__((ext_vector_type(16)));

#if __has_builtin(__builtin_amdgcn_exp2f)
#define EXP2(x) __builtin_amdgcn_exp2f(x)
#else
#define EXP2(x) exp2f(x)
#endif

__device__ __forceinline__ u16 f2bf(float f) {
  u32 u = __builtin_bit_cast(u32, f);
  u = (u + 0x7fffu + ((u >> 16) & 1u)) >> 16;
  return (u16)u;
}
__device__ __forceinline__ float bf2f(u16 h) {
  u32 u = ((u32)h) << 16;
  return __builtin_bit_cast(float, u);
}

__device__ __forceinline__ void gload_lds16(const void* g, void* l) {
  __builtin_amdgcn_global_load_lds(
      (__attribute__((address_space(1))) void*)(const_cast<void*>(g)),
      (__attribute__((address_space(3))) void*)(l), 16, 0, 0);
}

// ---------------- fused fp32 -> bf16 conversion (5 tensors, one grid) -----
__global__ __launch_bounds__(256) void cvt_all(const float* __restrict__ h,
                                               const float* __restrict__ wq,
                                               const float* __restrict__ wk,
                                               const float* __restrict__ wv,
                                               const float* __restrict__ wo,
                                               u16* __restrict__ hb,
                                               u16* __restrict__ wqkv,
                                               u16* __restrict__ wob) {
  int bx = blockIdx.x;
  const float* s; u16* d; int lb;
  if (bx < 7168)       { s = h;  d = hb;   lb = bx; }
  else if (bx < 13440) { s = wq; d = wqkv; lb = bx - 7168; }
  else if (bx < 14336) { s = wk; d = wqkv + (size_t)KOFF * HIDDEN; lb = bx - 13440; }
  else if (bx < 15232) { s = wv; d = wqkv + (size_t)VOFF * HIDDEN; lb = bx - 14336; }
  else                 { s = wo; d = wob;  lb = bx - 15232; }
  size_t i = ((size_t)lb * 256 + threadIdx.x) * 8;
  float4 a = *(const float4*)(s + i);
  float4 b = *(const float4*)(s + i + 4);
  u32 o0 = f2bf(a.x) | ((u32)f2bf(a.y) << 16);
  u32 o1 = f2bf(a.z) | ((u32)f2bf(a.w) << 16);
  u32 o2 = f2bf(b.x) | ((u32)f2bf(b.y) << 16);
  u32 o3 = f2bf(b.z) | ((u32)f2bf(b.w) << 16);
  uint4 o; o.x = o0; o.y = o1; o.z = o2; o.w = o3;
  *(uint4*)(d + i) = o;
}

// ---------------- RoPE: sincos table (2048 x 64) --------------------------
__global__ __launch_bounds__(256) void rope_tab(float2* __restrict__ tab) {
  int i = blockIdx.x * 256 + threadIdx.x;   // 131072
  int d = i & 63;
  float p = (float)(i >> 6);
  float freq = exp2f(-(float)d * (19.93156856932417f / 64.0f));
  float sv, cv;
  sincosf(p * freq, &sv, &cv);
  tab[i] = make_float2(cv, sv);
}

// ---------------- RoPE in-place, table-driven, bf16x8 vectorized ----------
// thread = (row, head, d8-group of 8): pairs (d, d+64) within head.
__global__ __launch_bounds__(256) void rope_ip8(u16* __restrict__ X,
                                                const int* __restrict__ pos,
                                                const float2* __restrict__ tab) {
  int i = blockIdx.x * 256 + threadIdx.x;
  int row = i >> 8;           // 256 groups per row (32 heads x 8)
  int g = i & 255;
  int head = g >> 3, d0 = (g & 7) * 8;
  u16* px = X + (size_t)row * QSTR + head * 128 + d0;
  u16x8 a = *(const u16x8*)px;
  u16x8 b = *(const u16x8*)(px + 64);
  const float2* t = tab + (pos[row] << 6) + d0;
#pragma unroll
  for (int e = 0; e < 8; e++) {
    float2 cs = t[e];
    float x1 = bf2f(a[e]), x2 = bf2f(b[e]);
    a[e] = f2bf(x1 * cs.x - x2 * cs.y);
    b[e] = f2bf(x2 * cs.x + x1 * cs.y);
  }
  *(u16x8*)px = a;
  *(u16x8*)(px + 64) = b;
}

// ---------------- bf16 GEMM 256x256, BK=64, 8-phase pipeline --------------
#define VMW6 asm volatile("s_waitcnt vmcnt(6)" ::: "memory")
#define NOP2 ((void)0)

#define PHASE(ABUF, BBUF, Q, S0, S1, VW)                                       \
  {                                                                            \
    bf16x8 a00 = *(const bf16x8*)((ABUF) + arow_b + (2*(Q))*2048 + col0);      \
    bf16x8 a01 = *(const bf16x8*)((ABUF) + arow_b + (2*(Q))*2048 + col1);      \
    bf16x8 a10 = *(const bf16x8*)((ABUF) + arow_b + (2*(Q)+1)*2048 + col0);    \
    bf16x8 a11 = *(const bf16x8*)((ABUF) + arow_b + (2*(Q)+1)*2048 + col1);    \
    if ((Q) == 0) {                                                            \
      bfr[0] = *(const bf16x8*)((BBUF) + brow_b + 0*2048 + col0);              \
      bfr[1] = *(const bf16x8*)((BBUF) + brow_b + 0*2048 + col1);              \
      bfr[2] = *(const bf16x8*)((BBUF) + brow_b + 1*2048 + col0);              \
      bfr[3] = *(const bf16x8*)((BBUF) + brow_b + 1*2048 + col1);              \
      bfr[4] = *(const bf16x8*)((BBUF) + brow_b + 2*2048 + col0);              \
      bfr[5] = *(const bf16x8*)((BBUF) + brow_b + 2*2048 + col1);              \
      bfr[6] = *(const bf16x8*)((BBUF) + brow_b + 3*2048 + col0);              \
      bfr[7] = *(const bf16x8*)((BBUF) + brow_b + 3*2048 + col1);              \
    }                                                                          \
    S0; S1;                                                                    \
    asm volatile("" ::: "memory");                                             \
    __builtin_amdgcn_s_barrier();                                              \
    asm volatile("" ::: "memory");                                             \
    __builtin_amdgcn_sched_barrier(0);                                         \
    __builtin_amdgcn_s_setprio(1);                                             \
    acc[2*(Q)][0]   = __builtin_amdgcn_mfma_f32_16x16x32_bf16(a00, bfr[0], acc[2*(Q)][0], 0, 0, 0);   \
    acc[2*(Q)][1]   = __builtin_amdgcn_mfma_f32_16x16x32_bf16(a00, bfr[2], acc[2*(Q)][1], 0, 0, 0);   \
    acc[2*(Q)][2]   = __builtin_amdgcn_mfma_f32_16x16x32_bf16(a00, bfr[4], acc[2*(Q)][2], 0, 0, 0);   \
    acc[2*(Q)][3]   = __builtin_amdgcn_mfma_f32_16x16x32_bf16(a00, bfr[6], acc[2*(Q)][3], 0, 0, 0);   \
    acc[2*(Q)+1][0] = __builtin_amdgcn_mfma_f32_16x16x32_bf16(a10, bfr[0], acc[2*(Q)+1][0], 0, 0, 0); \
    acc[2*(Q)+1][1] = __builtin_amdgcn_mfma_f32_16x16x32_bf16(a10, bfr[2], acc[2*(Q)+1][1], 0, 0, 0); \
    acc[2*(Q)+1][2] = __builtin_amdgcn_mfma_f32_16x16x32_bf16(a10, bfr[4], acc[2*(Q)+1][2], 0, 0, 0); \
    acc[2*(Q)+1][3] = __builtin_amdgcn_mfma_f32_16x16x32_bf16(a10, bfr[6], acc[2*(Q)+1][3], 0, 0, 0); \
    acc[2*(Q)][0]   = __builtin_amdgcn_mfma_f32_16x16x32_bf16(a01, bfr[1], acc[2*(Q)][0], 0, 0, 0);   \
    acc[2*(Q)][1]   = __builtin_amdgcn_mfma_f32_16x16x32_bf16(a01, bfr[3], acc[2*(Q)][1], 0, 0, 0);   \
    acc[2*(Q)][2]   = __builtin_amdgcn_mfma_f32_16x16x32_bf16(a01, bfr[5], acc[2*(Q)][2], 0, 0, 0);   \
    acc[2*(Q)][3]   = __builtin_amdgcn_mfma_f32_16x16x32_bf16(a01, bfr[7], acc[2*(Q)][3], 0, 0, 0);   \
    acc[2*(Q)+1][0] = __builtin_amdgcn_mfma_f32_16x16x32_bf16(a11, bfr[1], acc[2*(Q)+1][0], 0, 0, 0); \
    acc[2*(Q)+1][1] = __builtin_amdgcn_mfma_f32_16x16x32_bf16(a11, bfr[3], acc[2*(Q)+1][1], 0, 0, 0); \
    acc[2*(Q)+1][2] = __builtin_amdgcn_mfma_f32_16x16x32_bf16(a11, bfr[5], acc[2*(Q)+1][2], 0, 0, 0); \
    acc[2*(Q)+1][3] = __builtin_amdgcn_mfma_f32_16x16x32_bf16(a11, bfr[7], acc[2*(Q)+1][3], 0, 0, 0); \
    __builtin_amdgcn_s_setprio(0);                                             \
    VW;                                                                        \
    asm volatile("" ::: "memory");                                             \
    __builtin_amdgcn_s_barrier();                                              \
    asm volatile("" ::: "memory");                                             \
    __builtin_amdgcn_sched_barrier(0);                                         \
  }

template <bool OUTBF>
__global__ __launch_bounds__(512, 2) void gemm256(const u16* __restrict__ A,
                                                  const u16* __restrict__ B,
                                                  void* __restrict__ C,
                                                  int M, int N, int K, int tx) {
  __shared__ __align__(16) char lds[131072];
  const int tid = threadIdx.x;
  const int lane = tid & 63, wave = tid >> 6;
  const int fr = lane & 15, fq = lane >> 4;
  const int wm = wave >> 2, wn = wave & 3;

  const int nwg = gridDim.x;
  const int qq = nwg >> 3, r8 = nwg & 7;
  const int orig = blockIdx.x;
  const int xcd = orig & 7, idx = orig >> 3;
  const int wg = (xcd < r8) ? (xcd * (qq + 1) + idx)
                            : (r8 * (qq + 1) + (xcd - r8) * qq + idx);
  const int bx = wg % tx, by = wg / tx;
  const int aRow0 = by << 8, bCol0 = bx << 8;

  const size_t K2 = (size_t)K * 2;
  const int KT = K >> 6;
  const int NIT = KT >> 1;

  const int trow = tid >> 3;
  const int scol = ((tid & 7) * 16) ^ ((trow & 7) << 4);
  const char* Ab = (const char*)A + (size_t)(aRow0 + trow) * K2 + scol;
  const char* Bb = (const char*)B + (size_t)(bCol0 + trow) * K2 + scol;

  char* a0 = lds;
  char* b0 = lds + 32768;
  char* a1 = lds + 65536;
  char* b1 = lds + 98304;

#define STG_A(dst, gk, ra) gload_lds16(Ab + (size_t)(ra) * K2 + (size_t)(gk) * 128, (dst) + ((ra) << 7) + tid * 16)
#define STG_B(dst, gk, ra) gload_lds16(Bb + (size_t)(ra) * K2 + (size_t)(gk) * 128, (dst) + ((ra) << 7) + tid * 16)

  const int swzr = (fr & 7) << 4;
  const int col0 = (fq * 16) ^ swzr;
  const int col1 = (64 + fq * 16) ^ swzr;
  const int arow_b = (wm * 128 + fr) * 128;
  const int brow_b = (wn * 64 + fr) * 128;

  const f32x4 z4 = {0.f, 0.f, 0.f, 0.f};
  f32x4 acc[8][4];
#pragma unroll
  for (int i = 0; i < 8; i++)
#pragma unroll
    for (int j = 0; j < 4; j++) acc[i][j] = z4;
  bf16x8 bfr[8];

  STG_B(b0, 0, 0);   STG_B(b0, 0, 64);
  STG_B(b0, 0, 128); STG_B(b0, 0, 192);
  STG_A(a0, 0, 0);   STG_A(a0, 0, 128);
  STG_A(a0, 0, 64);  STG_A(a0, 0, 192);
  STG_B(b1, 1, 0);   STG_B(b1, 1, 64);
  STG_B(b1, 1, 128); STG_B(b1, 1, 192);
  STG_A(a1, 1, 0);   STG_A(a1, 1, 128);
  VMW6;
  asm volatile("" ::: "memory");
  __builtin_amdgcn_s_barrier();
  asm volatile("" ::: "memory");
  __builtin_amdgcn_sched_barrier(0);

  for (int it = 0; it < NIT; ++it) {
    const int G = it << 1;
    const int g2 = (G + 2 < KT) ? G + 2 : KT - 1;
    const int g3 = (G + 3 < KT) ? G + 3 : KT - 1;
    PHASE(a0, b0, 0, STG_A(a1, G + 1, 64), STG_A(a1, G + 1, 192), NOP2);
    PHASE(a0, b0, 1, STG_B(b0, g2, 0),     STG_B(b0, g2, 64),     NOP2);
    PHASE(a0, b0, 2, STG_B(b0, g2, 128),   STG_B(b0, g2, 192),    NOP2);
    PHASE(a0, b0, 3, STG_A(a0, g2, 0),     STG_A(a0, g2, 128),    VMW6);
    PHASE(a1, b1, 0, STG_A(a0, g2, 64),    STG_A(a0, g2, 192),    NOP2);
    PHASE(a1, b1, 1, STG_B(b1, g3, 0),     STG_B(b1, g3, 64),     NOP2);
    PHASE(a1, b1, 2, STG_B(b1, g3, 128),   STG_B(b1, g3, 192),    NOP2);
    PHASE(a1, b1, 3, STG_A(a1, g3, 0),     STG_A(a1, g3, 128),    VMW6);
  }

#pragma unroll
  for (int mi = 0; mi < 8; mi++)
#pragma unroll
    for (int ni = 0; ni < 4; ni++)
#pragma unroll
      for (int r2 = 0; r2 < 4; r2++) {
        int row = aRow0 + wm * 128 + mi * 16 + fq * 4 + r2;
        int col = bCol0 + wn * 64 + ni * 16 + fr;
        if (OUTBF)
          ((u16*)C)[(size_t)row * N + col] = f2bf(acc[mi][ni][r2]);
        else
          ((float*)C)[(size_t)row * N + col] = acc[mi][ni][r2];
      }
}

// ---------------- flash attention (causal, GQA) ---------------------------
// Uniform-work pairing: block bx handles q-subtiles (31-bx, bx) as two
// phases -> every block does exactly 33 KV-tile units (kills the triangle
// tail that pinned occupancy at 19.6%). Body = round-4 structure: 4 waves x
// 16 q-rows, KV tile 64, single-buffer 2-barrier loop, swapped QK^T.
// VALU trims: diagonal-only mask; exp2-domain softmax (fma+exp2, defer
// threshold 90.51 raw = e^8). LDS 40KB -> 4 blocks/CU.
__global__ __launch_bounds__(256, 4) void attn_fwd(const u16* __restrict__ QKV,
                                                   u16* __restrict__ Ob) {
  const int bxp = blockIdx.x;  // 0..15
  const int h = blockIdx.y, b = blockIdx.z;
  const int hkv = h / REP;
  const int tid = threadIdx.x, lane = tid & 63, wave = tid >> 6;
  const int fr = lane & 15, fq = lane >> 4;

  __shared__ u16 Ks[64 * 128];
  __shared__ u16 Vt[128 * 64];   // transposed: [d][kv]
  __shared__ u16 Ps[4 * 16 * 64];

  int kro[4], kco[4];
#pragma unroll
  for (int rd = 0; rd < 4; rd++) {
    int o = rd * 4096 + wave * 1024 + lane * 16;
    kro[rd] = o >> 8;
    kco[rd] = ((o & 255) ^ ((kro[rd] & 7) << 4)) >> 1;
  }
  const int vp = tid & 31;  // kv pair index (rows 2vp, 2vp+1)
  const int vc = tid >> 5;  // d chunk (16 wide), 0..7

  const float Cs = 0.12751741f;  // SCALE * log2(e)
  const f32x4 z4 = {0.f, 0.f, 0.f, 0.f};

  for (int ph = 0; ph < 2; ph++) {
    const int st = ph ? bxp : 31 - bxp;

    // Q fragments straight from global (wave-private q-rows)
    const int qr = wave * 16 + fr;
    const size_t qrow = (size_t)(b * SEQ + st * 64 + qr) * QSTR + h * HD;
    bf16x8 qf[4];
#pragma unroll
    for (int kc = 0; kc < 4; kc++)
      qf[kc] = *(const bf16x8*)(QKV + qrow + kc * 32 + fq * 8);

    float mr = -1e30f;   // running row max (RAW score units)
    float mC = 0.f;      // mr * Cs (set on first defer-trigger, j=0 always fires)
    float lp = 0.f;      // per-lane PARTIAL row sum
    f32x4 ov[8];
#pragma unroll
    for (int i = 0; i < 8; i++) ov[i] = z4;

    for (int j = 0; j <= st; j++) {
      const size_t base = (size_t)(b * SEQ + j * 64) * QSTR;
      const size_t kbase = base + KOFF + hkv * HD;
      const size_t vbase = base + VOFF + hkv * HD;
#pragma unroll
      for (int rd = 0; rd < 4; rd++)
        gload_lds16(QKV + kbase + (size_t)kro[rd] * QSTR + kco[rd],
                    (char*)Ks + (rd * 4096 + wave * 1024));
      {  // V transpose: rows 2vp/2vp+1, 16 d-columns each (32B loads)
        const u16* v0 = QKV + vbase + (size_t)(2 * vp) * QSTR + vc * 16;
        u16x16 ra = *(const u16x16*)v0;
        u16x16 rb = *(const u16x16*)(v0 + QSTR);
#pragma unroll
        for (int i = 0; i < 16; i++) {
          int d = vc * 16 + i;
          u32 val = (u32)ra[i] | ((u32)rb[i] << 16);
          *(u32*)((char*)Vt + d * 128 + ((vp * 4) ^ ((d & 7) << 4))) = val;
        }
      }
      __syncthreads();

      // S = K Q^T (swapped): sc[ni][r] = S_raw[k=j*64+ni*16+fq*4+r][q=wave*16+fr]
      f32x4 sc[4];
#pragma unroll
      for (int ni = 0; ni < 4; ni++) sc[ni] = z4;
#pragma unroll
      for (int kc = 0; kc < 4; kc++) {
#pragma unroll
        for (int ni = 0; ni < 4; ni++) {
          int kr = ni * 16 + fr;
          bf16x8 bk = *(const bf16x8*)((const char*)Ks + kr * 256 +
                                       ((kc * 64 + fq * 16) ^ ((kr & 7) << 4)));
          sc[ni] = __builtin_amdgcn_mfma_f32_16x16x32_bf16(bk, qf[kc], sc[ni], 0, 0, 0);
        }
      }

      // causal mask: only the diagonal tile needs it
      if (j == st) {
        const int rowg = st * 64 + wave * 16 + fr;
#pragma unroll
        for (int ni = 0; ni < 4; ni++)
#pragma unroll
          for (int r = 0; r < 4; r++) {
            int colg = j * 64 + ni * 16 + fq * 4 + r;
            if (colg > rowg) sc[ni][r] = -1e30f;
          }
      }

      // tile max (raw units): in-register tree + 2 cross-lane steps
      float pmax;
      {
        f32x4 m4 = sc[0];
#pragma unroll
        for (int ni = 1; ni < 4; ni++)
#pragma unroll
          for (int r = 0; r < 4; r++) m4[r] = fmaxf(m4[r], sc[ni][r]);
        pmax = fmaxf(fmaxf(m4[0], m4[1]), fmaxf(m4[2], m4[3]));
        pmax = fmaxf(pmax, __shfl_xor(pmax, 16));
        pmax = fmaxf(pmax, __shfl_xor(pmax, 32));
      }

      // defer-max: rescale only when tile max beats running max by > 8/SCALE
      if (__any(pmax > mr + 90.509668f)) {
        float mnew = fmaxf(mr, pmax);
        float sf = EXP2((mr - mnew) * Cs);
        mr = mnew;
        mC = mr * Cs;
        lp *= sf;
#pragma unroll
        for (int r = 0; r < 4; r++) {
          float sr = __shfl(sf, fq * 4 + r);
#pragma unroll
          for (int n2 = 0; n2 < 8; n2++) ov[n2][r] *= sr;
        }
      }

      // p = exp2(s*Cs - mC); partial-sum; pack bf16; P -> LDS (8 u32 stores)
      {
        char* pb = (char*)Ps + wave * 2048 + fr * 128;
        const int swz = (fr & 7) << 4;
        float lad = 0.f;
#pragma unroll
        for (int ni = 0; ni < 4; ni++) {
          float p0 = EXP2(fmaf(sc[ni][0], Cs, -mC));
          float p1 = EXP2(fmaf(sc[ni][1], Cs, -mC));
          float p2 = EXP2(fmaf(sc[ni][2], Cs, -mC));
          float p3 = EXP2(fmaf(sc[ni][3], Cs, -mC));
          lad += (p0 + p1) + (p2 + p3);
          bf16x2 w0 = {(__bf16)p0, (__bf16)p1};
          bf16x2 w1 = {(__bf16)p2, (__bf16)p3};
          int kb = ni * 32 + fq * 8;
          *(u32*)(pb + (kb ^ swz)) = __builtin_bit_cast(u32, w0);
          *(u32*)(pb + ((kb + 4) ^ swz)) = __builtin_bit_cast(u32, w1);
        }
        lp += lad;
      }

      // O += P V (16 MFMA / wave); ov rows q = fq*4+r, cols d = n2*16+fr
#pragma unroll
      for (int kc = 0; kc < 2; kc++) {
        bf16x8 ap = *(const bf16x8*)((const char*)Ps + wave * 2048 + fr * 128 +
                                     ((kc * 64 + fq * 16) ^ ((fr & 7) << 4)));
#pragma unroll
        for (int n2 = 0; n2 < 8; n2++) {
          int vd = n2 * 16 + fr;
          bf16x8 bv = *(const bf16x8*)((const char*)Vt + vd * 128 +
                                       ((kc * 64 + fq * 16) ^ ((vd & 7) << 4)));
          ov[n2] = __builtin_amdgcn_mfma_f32_16x16x32_bf16(ap, bv, ov[n2], 0, 0, 0);
        }
      }
      __syncthreads();
    }

    // final row-sum reduce + normalize + store (per phase)
    float ls = lp;
    ls += __shfl_xor(ls, 16);
    ls += __shfl_xor(ls, 32);
#pragma unroll
    for (int r = 0; r < 4; r++) {
      float lr = __shfl(ls, fq * 4 + r);
      float inv = 1.0f / lr;
      size_t rowg = (size_t)(b * SEQ + st * 64 + wave * 16 + fq * 4 + r) * HIDDEN + h * HD;
#pragma unroll
      for (int n2 = 0; n2 < 8; n2++)
        Ob[rowg + n2 * 16 + fr] = f2bf(ov[n2][r] * inv);
    }
  }
}

// ---------------- launch --------------------------------------------------
extern "C" void kernel_launch(void* const* d_in, const int* in_sizes, int n_in,
                              void* d_out, int out_size, void* d_ws, size_t ws_size,
                              hipStream_t stream) {
  const float* hidden = (const float*)d_in[0];
  // d_in[1] = attention_mask: exactly the causal mask -> applied analytically
  const int* pos = (const int*)d_in[2];
  const float* Wq = (const float*)d_in[3];
  const float* Wk = (const float*)d_in[4];
  const float* Wv = (const float*)d_in[5];
  const float* Wo = (const float*)d_in[6];
  float* out = (float*)d_out;
  char* ws = (char*)d_ws;

  // workspace layout (bytes), total 120 MiB
  u16* wqkv = (u16*)(ws + 0);         // [4608][3584] bf16
  u16* wob  = (u16*)(ws + 33030144);  // [3584][3584]
  u16* hb   = (u16*)(ws + 58720256);  // [4096][3584] hidden bf16; reused as attn out
  u16* attnb = hb;
  float2* tab = (float2*)(ws + 58720256);  // 1MB sincos table: lives in the dead
                                           // hb window (after QKV gemm, before attn)
  u16* qkv  = (u16*)(ws + 88080384);  // [4096][4608] fused Q|K|V

  cvt_all<<<21504, 256, 0, stream>>>(hidden, Wq, Wk, Wv, Wo, hb, wqkv, wob);

  // fused QKV projection: [4096, 4608] = hb[4096,3584] @ wqkv^T
  gemm256<true><<<288, 512, 0, stream>>>(hb, wqkv, qkv, 4096, QSTR, HIDDEN, 18);

  // RoPE: build table (hb now dead), then apply to Q+K heads
  rope_tab<<<512, 256, 0, stream>>>(tab);
  rope_ip8<<<4096, 256, 0, stream>>>(qkv, pos, tab);

  attn_fwd<<<dim3(16, NH, NB), 256, 0, stream>>>(qkv, attnb);

  gemm256<false><<<224, 512, 0, stream>>>(attnb, wob, out, 4096, HIDDEN, HIDDEN, 14);
}

// Round 12
// 440.410 us; speedup vs baseline: 1.0002x; 1.0002x over previous
//
#include <hip/hip_runtime.h>
#include <cstdint>
#include <cstddef>

#define HIDDEN 3584
#define NH 28
#define NKV 4
#define HD 128
#define SEQ 2048
#define NB 2
#define REP (NH / NKV)   // 7
#define QSTR 4608        // fused qkv row stride (3584 + 512 + 512)
#define KOFF 3584
#define VOFF 4096

typedef unsigned short u16;
typedef unsigned int u32;
typedef __bf16 bf16x8 __attribute__((ext_vector_type(8)));
typedef __bf16 bf16x2 __attribute__((ext_vector_type(2)));
typedef float f32x4 __attribute__((ext_vector_type(4)));
typedef u16 u16x8 __attribute__((ext_vector_type(8)));
typedef u16 u16x16 __attribute__((ext_vector_type(16)));

#if __has_builtin(__builtin_amdgcn_exp2f)
#define EXP2(x) __builtin_amdgcn_exp2f(x)
#else
#define EXP2(x) exp2f(x)
#endif

__device__ __forceinline__ u16 f2bf(float f) {
  u32 u = __builtin_bit_cast(u32, f);
  u = (u + 0x7fffu + ((u >> 16) & 1u)) >> 16;
  return (u16)u;
}
__device__ __forceinline__ float bf2f(u16 h) {
  u32 u = ((u32)h) << 16;
  return __builtin_bit_cast(float, u);
}

__device__ __forceinline__ void gload_lds16(const void* g, void* l) {
  __builtin_amdgcn_global_load_lds(
      (__attribute__((address_space(1))) void*)(const_cast<void*>(g)),
      (__attribute__((address_space(3))) void*)(l), 16, 0, 0);
}

// ---------------- fused fp32 -> bf16 conversion (5 tensors, one grid) -----
__global__ __launch_bounds__(256) void cvt_all(const float* __restrict__ h,
                                               const float* __restrict__ wq,
                                               const float* __restrict__ wk,
                                               const float* __restrict__ wv,
                                               const float* __restrict__ wo,
                                               u16* __restrict__ hb,
                                               u16* __restrict__ wqkv,
                                               u16* __restrict__ wob) {
  int bx = blockIdx.x;
  const float* s; u16* d; int lb;
  if (bx < 7168)       { s = h;  d = hb;   lb = bx; }
  else if (bx < 13440) { s = wq; d = wqkv; lb = bx - 7168; }
  else if (bx < 14336) { s = wk; d = wqkv + (size_t)KOFF * HIDDEN; lb = bx - 13440; }
  else if (bx < 15232) { s = wv; d = wqkv + (size_t)VOFF * HIDDEN; lb = bx - 14336; }
  else                 { s = wo; d = wob;  lb = bx - 15232; }
  size_t i = ((size_t)lb * 256 + threadIdx.x) * 8;
  float4 a = *(const float4*)(s + i);
  float4 b = *(const float4*)(s + i + 4);
  u32 o0 = f2bf(a.x) | ((u32)f2bf(a.y) << 16);
  u32 o1 = f2bf(a.z) | ((u32)f2bf(a.w) << 16);
  u32 o2 = f2bf(b.x) | ((u32)f2bf(b.y) << 16);
  u32 o3 = f2bf(b.z) | ((u32)f2bf(b.w) << 16);
  uint4 o; o.x = o0; o.y = o1; o.z = o2; o.w = o3;
  *(uint4*)(d + i) = o;
}

// ---------------- RoPE: sincos table (2048 x 64) --------------------------
__global__ __launch_bounds__(256) void rope_tab(float2* __restrict__ tab) {
  int i = blockIdx.x * 256 + threadIdx.x;   // 131072
  int d = i & 63;
  float p = (float)(i >> 6);
  float freq = exp2f(-(float)d * (19.93156856932417f / 64.0f));
  float sv, cv;
  sincosf(p * freq, &sv, &cv);
  tab[i] = make_float2(cv, sv);
}

// ---------------- RoPE in-place, table-driven, bf16x8 vectorized ----------
// thread = (row, head, d8-group of 8): pairs (d, d+64) within head.
__global__ __launch_bounds__(256) void rope_ip8(u16* __restrict__ X,
                                                const int* __restrict__ pos,
                                                const float2* __restrict__ tab) {
  int i = blockIdx.x * 256 + threadIdx.x;
  int row = i >> 8;           // 256 groups per row (32 heads x 8)
  int g = i & 255;
  int head = g >> 3, d0 = (g & 7) * 8;
  u16* px = X + (size_t)row * QSTR + head * 128 + d0;
  u16x8 a = *(const u16x8*)px;
  u16x8 b = *(const u16x8*)(px + 64);
  const float2* t = tab + (pos[row] << 6) + d0;
#pragma unroll
  for (int e = 0; e < 8; e++) {
    float2 cs = t[e];
    float x1 = bf2f(a[e]), x2 = bf2f(b[e]);
    a[e] = f2bf(x1 * cs.x - x2 * cs.y);
    b[e] = f2bf(x2 * cs.x + x1 * cs.y);
  }
  *(u16x8*)px = a;
  *(u16x8*)(px + 64) = b;
}

// ---------------- bf16 GEMM 256x256, BK=64, 8-phase pipeline --------------
#define VMW6 asm volatile("s_waitcnt vmcnt(6)" ::: "memory")
#define NOP2 ((void)0)

#define PHASE(ABUF, BBUF, Q, S0, S1, VW)                                       \
  {                                                                            \
    bf16x8 a00 = *(const bf16x8*)((ABUF) + arow_b + (2*(Q))*2048 + col0);      \
    bf16x8 a01 = *(const bf16x8*)((ABUF) + arow_b + (2*(Q))*2048 + col1);      \
    bf16x8 a10 = *(const bf16x8*)((ABUF) + arow_b + (2*(Q)+1)*2048 + col0);    \
    bf16x8 a11 = *(const bf16x8*)((ABUF) + arow_b + (2*(Q)+1)*2048 + col1);    \
    if ((Q) == 0) {                                                            \
      bfr[0] = *(const bf16x8*)((BBUF) + brow_b + 0*2048 + col0);              \
      bfr[1] = *(const bf16x8*)((BBUF) + brow_b + 0*2048 + col1);              \
      bfr[2] = *(const bf16x8*)((BBUF) + brow_b + 1*2048 + col0);              \
      bfr[3] = *(const bf16x8*)((BBUF) + brow_b + 1*2048 + col1);              \
      bfr[4] = *(const bf16x8*)((BBUF) + brow_b + 2*2048 + col0);              \
      bfr[5] = *(const bf16x8*)((BBUF) + brow_b + 2*2048 + col1);              \
      bfr[6] = *(const bf16x8*)((BBUF) + brow_b + 3*2048 + col0);              \
      bfr[7] = *(const bf16x8*)((BBUF) + brow_b + 3*2048 + col1);              \
    }                                                                          \
    S0; S1;                                                                    \
    asm volatile("" ::: "memory");                                             \
    __builtin_amdgcn_s_barrier();                                              \
    asm volatile("" ::: "memory");                                             \
    __builtin_amdgcn_sched_barrier(0);                                         \
    __builtin_amdgcn_s_setprio(1);                                             \
    acc[2*(Q)][0]   = __builtin_amdgcn_mfma_f32_16x16x32_bf16(a00, bfr[0], acc[2*(Q)][0], 0, 0, 0);   \
    acc[2*(Q)][1]   = __builtin_amdgcn_mfma_f32_16x16x32_bf16(a00, bfr[2], acc[2*(Q)][1], 0, 0, 0);   \
    acc[2*(Q)][2]   = __builtin_amdgcn_mfma_f32_16x16x32_bf16(a00, bfr[4], acc[2*(Q)][2], 0, 0, 0);   \
    acc[2*(Q)][3]   = __builtin_amdgcn_mfma_f32_16x16x32_bf16(a00, bfr[6], acc[2*(Q)][3], 0, 0, 0);   \
    acc[2*(Q)+1][0] = __builtin_amdgcn_mfma_f32_16x16x32_bf16(a10, bfr[0], acc[2*(Q)+1][0], 0, 0, 0); \
    acc[2*(Q)+1][1] = __builtin_amdgcn_mfma_f32_16x16x32_bf16(a10, bfr[2], acc[2*(Q)+1][1], 0, 0, 0); \
    acc[2*(Q)+1][2] = __builtin_amdgcn_mfma_f32_16x16x32_bf16(a10, bfr[4], acc[2*(Q)+1][2], 0, 0, 0); \
    acc[2*(Q)+1][3] = __builtin_amdgcn_mfma_f32_16x16x32_bf16(a10, bfr[6], acc[2*(Q)+1][3], 0, 0, 0); \
    acc[2*(Q)][0]   = __builtin_amdgcn_mfma_f32_16x16x32_bf16(a01, bfr[1], acc[2*(Q)][0], 0, 0, 0);   \
    acc[2*(Q)][1]   = __builtin_amdgcn_mfma_f32_16x16x32_bf16(a01, bfr[3], acc[2*(Q)][1], 0, 0, 0);   \
    acc[2*(Q)][2]   = __builtin_amdgcn_mfma_f32_16x16x32_bf16(a01, bfr[5], acc[2*(Q)][2], 0, 0, 0);   \
    acc[2*(Q)][3]   = __builtin_amdgcn_mfma_f32_16x16x32_bf16(a01, bfr[7], acc[2*(Q)][3], 0, 0, 0);   \
    acc[2*(Q)+1][0] = __builtin_amdgcn_mfma_f32_16x16x32_bf16(a11, bfr[1], acc[2*(Q)+1][0], 0, 0, 0); \
    acc[2*(Q)+1][1] = __builtin_amdgcn_mfma_f32_16x16x32_bf16(a11, bfr[3], acc[2*(Q)+1][1], 0, 0, 0); \
    acc[2*(Q)+1][2] = __builtin_amdgcn_mfma_f32_16x16x32_bf16(a11, bfr[5], acc[2*(Q)+1][2], 0, 0, 0); \
    acc[2*(Q)+1][3] = __builtin_amdgcn_mfma_f32_16x16x32_bf16(a11, bfr[7], acc[2*(Q)+1][3], 0, 0, 0); \
    __builtin_amdgcn_s_setprio(0);                                             \
    VW;                                                                        \
    asm volatile("" ::: "memory");                                             \
    __builtin_amdgcn_s_barrier();                                              \
    asm volatile("" ::: "memory");                                             \
    __builtin_amdgcn_sched_barrier(0);                                         \
  }

template <bool OUTBF>
__global__ __launch_bounds__(512, 2) void gemm256(const u16* __restrict__ A,
                                                  const u16* __restrict__ B,
                                                  void* __restrict__ C,
                                                  int M, int N, int K, int tx) {
  __shared__ __align__(16) char lds[131072];
  const int tid = threadIdx.x;
  const int lane = tid & 63, wave = tid >> 6;
  const int fr = lane & 15, fq = lane >> 4;
  const int wm = wave >> 2, wn = wave & 3;

  const int nwg = gridDim.x;
  const int qq = nwg >> 3, r8 = nwg & 7;
  const int orig = blockIdx.x;
  const int xcd = orig & 7, idx = orig >> 3;
  const int wg = (xcd < r8) ? (xcd * (qq + 1) + idx)
                            : (r8 * (qq + 1) + (xcd - r8) * qq + idx);
  const int bx = wg % tx, by = wg / tx;
  const int aRow0 = by << 8, bCol0 = bx << 8;

  const size_t K2 = (size_t)K * 2;
  const int KT = K >> 6;
  const int NIT = KT >> 1;

  const int trow = tid >> 3;
  const int scol = ((tid & 7) * 16) ^ ((trow & 7) << 4);
  const char* Ab = (const char*)A + (size_t)(aRow0 + trow) * K2 + scol;
  const char* Bb = (const char*)B + (size_t)(bCol0 + trow) * K2 + scol;

  char* a0 = lds;
  char* b0 = lds + 32768;
  char* a1 = lds + 65536;
  char* b1 = lds + 98304;

#define STG_A(dst, gk, ra) gload_lds16(Ab + (size_t)(ra) * K2 + (size_t)(gk) * 128, (dst) + ((ra) << 7) + tid * 16)
#define STG_B(dst, gk, ra) gload_lds16(Bb + (size_t)(ra) * K2 + (size_t)(gk) * 128, (dst) + ((ra) << 7) + tid * 16)

  const int swzr = (fr & 7) << 4;
  const int col0 = (fq * 16) ^ swzr;
  const int col1 = (64 + fq * 16) ^ swzr;
  const int arow_b = (wm * 128 + fr) * 128;
  const int brow_b = (wn * 64 + fr) * 128;

  const f32x4 z4 = {0.f, 0.f, 0.f, 0.f};
  f32x4 acc[8][4];
#pragma unroll
  for (int i = 0; i < 8; i++)
#pragma unroll
    for (int j = 0; j < 4; j++) acc[i][j] = z4;
  bf16x8 bfr[8];

  STG_B(b0, 0, 0);   STG_B(b0, 0, 64);
  STG_B(b0, 0, 128); STG_B(b0, 0, 192);
  STG_A(a0, 0, 0);   STG_A(a0, 0, 128);
  STG_A(a0, 0, 64);  STG_A(a0, 0, 192);
  STG_B(b1, 1, 0);   STG_B(b1, 1, 64);
  STG_B(b1, 1, 128); STG_B(b1, 1, 192);
  STG_A(a1, 1, 0);   STG_A(a1, 1, 128);
  VMW6;
  asm volatile("" ::: "memory");
  __builtin_amdgcn_s_barrier();
  asm volatile("" ::: "memory");
  __builtin_amdgcn_sched_barrier(0);

  for (int it = 0; it < NIT; ++it) {
    const int G = it << 1;
    const int g2 = (G + 2 < KT) ? G + 2 : KT - 1;
    const int g3 = (G + 3 < KT) ? G + 3 : KT - 1;
    PHASE(a0, b0, 0, STG_A(a1, G + 1, 64), STG_A(a1, G + 1, 192), NOP2);
    PHASE(a0, b0, 1, STG_B(b0, g2, 0),     STG_B(b0, g2, 64),     NOP2);
    PHASE(a0, b0, 2, STG_B(b0, g2, 128),   STG_B(b0, g2, 192),    NOP2);
    PHASE(a0, b0, 3, STG_A(a0, g2, 0),     STG_A(a0, g2, 128),    VMW6);
    PHASE(a1, b1, 0, STG_A(a0, g2, 64),    STG_A(a0, g2, 192),    NOP2);
    PHASE(a1, b1, 1, STG_B(b1, g3, 0),     STG_B(b1, g3, 64),     NOP2);
    PHASE(a1, b1, 2, STG_B(b1, g3, 128),   STG_B(b1, g3, 192),    NOP2);
    PHASE(a1, b1, 3, STG_A(a1, g3, 0),     STG_A(a1, g3, 128),    VMW6);
  }

#pragma unroll
  for (int mi = 0; mi < 8; mi++)
#pragma unroll
    for (int ni = 0; ni < 4; ni++)
#pragma unroll
      for (int r2 = 0; r2 < 4; r2++) {
        int row = aRow0 + wm * 128 + mi * 16 + fq * 4 + r2;
        int col = bCol0 + wn * 64 + ni * 16 + fr;
        if (OUTBF)
          ((u16*)C)[(size_t)row * N + col] = f2bf(acc[mi][ni][r2]);
        else
          ((float*)C)[(size_t)row * N + col] = acc[mi][ni][r2];
      }
}

// ---------------- flash attention (causal, GQA) ---------------------------
// Uniform-work pairing: block bx handles q-subtiles (31-bx, bx) as two
// phases -> every block does exactly 33 KV-tile units (kills the triangle
// tail that pinned occupancy at 19.6%). Body = round-4 structure: 4 waves x
// 16 q-rows, KV tile 64, single-buffer 2-barrier loop, swapped QK^T.
// VALU trims: diagonal-only mask; exp2-domain softmax (fma+exp2, defer
// threshold 90.51 raw = e^8). LDS 40KB -> 4 blocks/CU.
__global__ __launch_bounds__(256, 4) void attn_fwd(const u16* __restrict__ QKV,
                                                   u16* __restrict__ Ob) {
  const int bxp = blockIdx.x;  // 0..15
  const int h = blockIdx.y, b = blockIdx.z;
  const int hkv = h / REP;
  const int tid = threadIdx.x, lane = tid & 63, wave = tid >> 6;
  const int fr = lane & 15, fq = lane >> 4;

  __shared__ u16 Ks[64 * 128];
  __shared__ u16 Vt[128 * 64];   // transposed: [d][kv]
  __shared__ u16 Ps[4 * 16 * 64];

  int kro[4], kco[4];
#pragma unroll
  for (int rd = 0; rd < 4; rd++) {
    int o = rd * 4096 + wave * 1024 + lane * 16;
    kro[rd] = o >> 8;
    kco[rd] = ((o & 255) ^ ((kro[rd] & 7) << 4)) >> 1;
  }
  const int vp = tid & 31;  // kv pair index (rows 2vp, 2vp+1)
  const int vc = tid >> 5;  // d chunk (16 wide), 0..7

  const float Cs = 0.12751741f;  // SCALE * log2(e)
  const f32x4 z4 = {0.f, 0.f, 0.f, 0.f};

  for (int ph = 0; ph < 2; ph++) {
    const int st = ph ? bxp : 31 - bxp;

    // Q fragments straight from global (wave-private q-rows)
    const int qr = wave * 16 + fr;
    const size_t qrow = (size_t)(b * SEQ + st * 64 + qr) * QSTR + h * HD;
    bf16x8 qf[4];
#pragma unroll
    for (int kc = 0; kc < 4; kc++)
      qf[kc] = *(const bf16x8*)(QKV + qrow + kc * 32 + fq * 8);

    float mr = -1e30f;   // running row max (RAW score units)
    float mC = 0.f;      // mr * Cs (set on first defer-trigger, j=0 always fires)
    float lp = 0.f;      // per-lane PARTIAL row sum
    f32x4 ov[8];
#pragma unroll
    for (int i = 0; i < 8; i++) ov[i] = z4;

    for (int j = 0; j <= st; j++) {
      const size_t base = (size_t)(b * SEQ + j * 64) * QSTR;
      const size_t kbase = base + KOFF + hkv * HD;
      const size_t vbase = base + VOFF + hkv * HD;
#pragma unroll
      for (int rd = 0; rd < 4; rd++)
        gload_lds16(QKV + kbase + (size_t)kro[rd] * QSTR + kco[rd],
                    (char*)Ks + (rd * 4096 + wave * 1024));
      {  // V transpose: rows 2vp/2vp+1, 16 d-columns each (32B loads)
        const u16* v0 = QKV + vbase + (size_t)(2 * vp) * QSTR + vc * 16;
        u16x16 ra = *(const u16x16*)v0;
        u16x16 rb = *(const u16x16*)(v0 + QSTR);
#pragma unroll
        for (int i = 0; i < 16; i++) {
          int d = vc * 16 + i;
          u32 val = (u32)ra[i] | ((u32)rb[i] << 16);
          *(u32*)((char*)Vt + d * 128 + ((vp * 4) ^ ((d & 7) << 4))) = val;
        }
      }
      __syncthreads();

      // S = K Q^T (swapped): sc[ni][r] = S_raw[k=j*64+ni*16+fq*4+r][q=wave*16+fr]
      f32x4 sc[4];
#pragma unroll
      for (int ni = 0; ni < 4; ni++) sc[ni] = z4;
#pragma unroll
      for (int kc = 0; kc < 4; kc++) {
#pragma unroll
        for (int ni = 0; ni < 4; ni++) {
          int kr = ni * 16 + fr;
          bf16x8 bk = *(const bf16x8*)((const char*)Ks + kr * 256 +
                                       ((kc * 64 + fq * 16) ^ ((kr & 7) << 4)));
          sc[ni] = __builtin_amdgcn_mfma_f32_16x16x32_bf16(bk, qf[kc], sc[ni], 0, 0, 0);
        }
      }

      // causal mask: only the diagonal tile needs it
      if (j == st) {
        const int rowg = st * 64 + wave * 16 + fr;
#pragma unroll
        for (int ni = 0; ni < 4; ni++)
#pragma unroll
          for (int r = 0; r < 4; r++) {
            int colg = j * 64 + ni * 16 + fq * 4 + r;
            if (colg > rowg) sc[ni][r] = -1e30f;
          }
      }

      // tile max (raw units): in-register tree + 2 cross-lane steps
      float pmax;
      {
        f32x4 m4 = sc[0];
#pragma unroll
        for (int ni = 1; ni < 4; ni++)
#pragma unroll
          for (int r = 0; r < 4; r++) m4[r] = fmaxf(m4[r], sc[ni][r]);
        pmax = fmaxf(fmaxf(m4[0], m4[1]), fmaxf(m4[2], m4[3]));
        pmax = fmaxf(pmax, __shfl_xor(pmax, 16));
        pmax = fmaxf(pmax, __shfl_xor(pmax, 32));
      }

      // defer-max: rescale only when tile max beats running max by > 8/SCALE
      if (__any(pmax > mr + 90.509668f)) {
        float mnew = fmaxf(mr, pmax);
        float sf = EXP2((mr - mnew) * Cs);
        mr = mnew;
        mC = mr * Cs;
        lp *= sf;
#pragma unroll
        for (int r = 0; r < 4; r++) {
          float sr = __shfl(sf, fq * 4 + r);
#pragma unroll
          for (int n2 = 0; n2 < 8; n2++) ov[n2][r] *= sr;
        }
      }

      // p = exp2(s*Cs - mC); partial-sum; pack bf16; P -> LDS (8 u32 stores)
      {
        char* pb = (char*)Ps + wave * 2048 + fr * 128;
        const int swz = (fr & 7) << 4;
        float lad = 0.f;
#pragma unroll
        for (int ni = 0; ni < 4; ni++) {
          float p0 = EXP2(fmaf(sc[ni][0], Cs, -mC));
          float p1 = EXP2(fmaf(sc[ni][1], Cs, -mC));
          float p2 = EXP2(fmaf(sc[ni][2], Cs, -mC));
          float p3 = EXP2(fmaf(sc[ni][3], Cs, -mC));
          lad += (p0 + p1) + (p2 + p3);
          bf16x2 w0 = {(__bf16)p0, (__bf16)p1};
          bf16x2 w1 = {(__bf16)p2, (__bf16)p3};
          int kb = ni * 32 + fq * 8;
          *(u32*)(pb + (kb ^ swz)) = __builtin_bit_cast(u32, w0);
          *(u32*)(pb + ((kb + 4) ^ swz)) = __builtin_bit_cast(u32, w1);
        }
        lp += lad;
      }

      // O += P V (16 MFMA / wave); ov rows q = fq*4+r, cols d = n2*16+fr
#pragma unroll
      for (int kc = 0; kc < 2; kc++) {
        bf16x8 ap = *(const bf16x8*)((const char*)Ps + wave * 2048 + fr * 128 +
                                     ((kc * 64 + fq * 16) ^ ((fr & 7) << 4)));
#pragma unroll
        for (int n2 = 0; n2 < 8; n2++) {
          int vd = n2 * 16 + fr;
          bf16x8 bv = *(const bf16x8*)((const char*)Vt + vd * 128 +
                                       ((kc * 64 + fq * 16) ^ ((vd & 7) << 4)));
          ov[n2] = __builtin_amdgcn_mfma_f32_16x16x32_bf16(ap, bv, ov[n2], 0, 0, 0);
        }
      }
      __syncthreads();
    }

    // final row-sum reduce + normalize + store (per phase)
    float ls = lp;
    ls += __shfl_xor(ls, 16);
    ls += __shfl_xor(ls, 32);
#pragma unroll
    for (int r = 0; r < 4; r++) {
      float lr = __shfl(ls, fq * 4 + r);
      float inv = 1.0f / lr;
      size_t rowg = (size_t)(b * SEQ + st * 64 + wave * 16 + fq * 4 + r) * HIDDEN + h * HD;
#pragma unroll
      for (int n2 = 0; n2 < 8; n2++)
        Ob[rowg + n2 * 16 + fr] = f2bf(ov[n2][r] * inv);
    }
  }
}

// ---------------- launch --------------------------------------------------
extern "C" void kernel_launch(void* const* d_in, const int* in_sizes, int n_in,
                              void* d_out, int out_size, void* d_ws, size_t ws_size,
                              hipStream_t stream) {
  const float* hidden = (const float*)d_in[0];
  // d_in[1] = attention_mask: exactly the causal mask -> applied analytically
  const int* pos = (const int*)d_in[2];
  const float* Wq = (const float*)d_in[3];
  const float* Wk = (const float*)d_in[4];
  const float* Wv = (const float*)d_in[5];
  const float* Wo = (const float*)d_in[6];
  float* out = (float*)d_out;
  char* ws = (char*)d_ws;

  // workspace layout (bytes), total 120 MiB
  u16* wqkv = (u16*)(ws + 0);         // [4608][3584] bf16
  u16* wob  = (u16*)(ws + 33030144);  // [3584][3584]
  u16* hb   = (u16*)(ws + 58720256);  // [4096][3584] hidden bf16; reused as attn out
  u16* attnb = hb;
  float2* tab = (float2*)(ws + 58720256);  // 1MB sincos table: lives in the dead
                                           // hb window (after QKV gemm, before attn)
  u16* qkv  = (u16*)(ws + 88080384);  // [4096][4608] fused Q|K|V

  cvt_all<<<21504, 256, 0, stream>>>(hidden, Wq, Wk, Wv, Wo, hb, wqkv, wob);

  // fused QKV projection: [4096, 4608] = hb[4096,3584] @ wqkv^T
  gemm256<true><<<288, 512, 0, stream>>>(hb, wqkv, qkv, 4096, QSTR, HIDDEN, 18);

  // RoPE: build table (hb now dead), then apply to Q+K heads
  rope_tab<<<512, 256, 0, stream>>>(tab);
  rope_ip8<<<4096, 256, 0, stream>>>(qkv, pos, tab);

  attn_fwd<<<dim3(16, NH, NB), 256, 0, stream>>>(qkv, attnb);

  gemm256<false><<<224, 512, 0, stream>>>(attnb, wob, out, 4096, HIDDEN, HIDDEN, 14);
}

// Round 13
// 440.324 us; speedup vs baseline: 1.0004x; 1.0002x over previous
//
#include <hip/hip_runtime.h>
#include <cstdint>
#include <cstddef>

#define HIDDEN 3584
#define NH 28
#define NKV 4
#define HD 128
#define SEQ 2048
#define NB 2
#define REP (NH / NKV)   // 7
#define QSTR 4608        // fused qkv row stride (3584 + 512 + 512)
#define KOFF 3584
#define VOFF 4096

typedef unsigned short u16;
typedef unsigned int u32;
typedef __bf16 bf16x8 __attribute__((ext_vector_type(8)));
typedef __bf16 bf16x2 __attribute__((ext_vector_type(2)));
typedef float f32x4 __attribute__((ext_vector_type(4)));
typedef u16 u16x8 __attribute__((ext_vector_type(8)));
typedef u16 u16x16 __attribute__((ext_vector_type(16)));

#if __has_builtin(__builtin_amdgcn_exp2f)
#define EXP2(x) __builtin_amdgcn_exp2f(x)
#else
#define EXP2(x) exp2f(x)
#endif

__device__ __forceinline__ u16 f2bf(float f) {
  u32 u = __builtin_bit_cast(u32, f);
  u = (u + 0x7fffu + ((u >> 16) & 1u)) >> 16;
  return (u16)u;
}
__device__ __forceinline__ float bf2f(u16 h) {
  u32 u = ((u32)h) << 16;
  return __builtin_bit_cast(float, u);
}

__device__ __forceinline__ void gload_lds16(const void* g, void* l) {
  __builtin_amdgcn_global_load_lds(
      (__attribute__((address_space(1))) void*)(const_cast<void*>(g)),
      (__attribute__((address_space(3))) void*)(l), 16, 0, 0);
}

// ---------------- fused fp32 -> bf16 conversion (5 tensors, one grid) -----
__global__ __launch_bounds__(256) void cvt_all(const float* __restrict__ h,
                                               const float* __restrict__ wq,
                                               const float* __restrict__ wk,
                                               const float* __restrict__ wv,
                                               const float* __restrict__ wo,
                                               u16* __restrict__ hb,
                                               u16* __restrict__ wqkv,
                                               u16* __restrict__ wob) {
  int bx = blockIdx.x;
  const float* s; u16* d; int lb;
  if (bx < 7168)       { s = h;  d = hb;   lb = bx; }
  else if (bx < 13440) { s = wq; d = wqkv; lb = bx - 7168; }
  else if (bx < 14336) { s = wk; d = wqkv + (size_t)KOFF * HIDDEN; lb = bx - 13440; }
  else if (bx < 15232) { s = wv; d = wqkv + (size_t)VOFF * HIDDEN; lb = bx - 14336; }
  else                 { s = wo; d = wob;  lb = bx - 15232; }
  size_t i = ((size_t)lb * 256 + threadIdx.x) * 8;
  float4 a = *(const float4*)(s + i);
  float4 b = *(const float4*)(s + i + 4);
  u32 o0 = f2bf(a.x) | ((u32)f2bf(a.y) << 16);
  u32 o1 = f2bf(a.z) | ((u32)f2bf(a.w) << 16);
  u32 o2 = f2bf(b.x) | ((u32)f2bf(b.y) << 16);
  u32 o3 = f2bf(b.z) | ((u32)f2bf(b.w) << 16);
  uint4 o; o.x = o0; o.y = o1; o.z = o2; o.w = o3;
  *(uint4*)(d + i) = o;
}

// ---------------- RoPE: sincos table (2048 x 64) --------------------------
__global__ __launch_bounds__(256) void rope_tab(float2* __restrict__ tab) {
  int i = blockIdx.x * 256 + threadIdx.x;   // 131072
  int d = i & 63;
  float p = (float)(i >> 6);
  float freq = exp2f(-(float)d * (19.93156856932417f / 64.0f));
  float sv, cv;
  sincosf(p * freq, &sv, &cv);
  tab[i] = make_float2(cv, sv);
}

// ---------------- RoPE in-place, table-driven, bf16x8 vectorized ----------
// thread = (row, head, d8-group of 8): pairs (d, d+64) within head.
__global__ __launch_bounds__(256) void rope_ip8(u16* __restrict__ X,
                                                const int* __restrict__ pos,
                                                const float2* __restrict__ tab) {
  int i = blockIdx.x * 256 + threadIdx.x;
  int row = i >> 8;           // 256 groups per row (32 heads x 8)
  int g = i & 255;
  int head = g >> 3, d0 = (g & 7) * 8;
  u16* px = X + (size_t)row * QSTR + head * 128 + d0;
  u16x8 a = *(const u16x8*)px;
  u16x8 b = *(const u16x8*)(px + 64);
  const float2* t = tab + (pos[row] << 6) + d0;
#pragma unroll
  for (int e = 0; e < 8; e++) {
    float2 cs = t[e];
    float x1 = bf2f(a[e]), x2 = bf2f(b[e]);
    a[e] = f2bf(x1 * cs.x - x2 * cs.y);
    b[e] = f2bf(x2 * cs.x + x1 * cs.y);
  }
  *(u16x8*)px = a;
  *(u16x8*)(px + 64) = b;
}

// ---------------- bf16 GEMM 256x256, BK=64, 8-phase pipeline --------------
#define VMW6 asm volatile("s_waitcnt vmcnt(6)" ::: "memory")
#define NOP2 ((void)0)

#define PHASE(ABUF, BBUF, Q, S0, S1, VW)                                       \
  {                                                                            \
    bf16x8 a00 = *(const bf16x8*)((ABUF) + arow_b + (2*(Q))*2048 + col0);      \
    bf16x8 a01 = *(const bf16x8*)((ABUF) + arow_b + (2*(Q))*2048 + col1);      \
    bf16x8 a10 = *(const bf16x8*)((ABUF) + arow_b + (2*(Q)+1)*2048 + col0);    \
    bf16x8 a11 = *(const bf16x8*)((ABUF) + arow_b + (2*(Q)+1)*2048 + col1);    \
    if ((Q) == 0) {                                                            \
      bfr[0] = *(const bf16x8*)((BBUF) + brow_b + 0*2048 + col0);              \
      bfr[1] = *(const bf16x8*)((BBUF) + brow_b + 0*2048 + col1);              \
      bfr[2] = *(const bf16x8*)((BBUF) + brow_b + 1*2048 + col0);              \
      bfr[3] = *(const bf16x8*)((BBUF) + brow_b + 1*2048 + col1);              \
      bfr[4] = *(const bf16x8*)((BBUF) + brow_b + 2*2048 + col0);              \
      bfr[5] = *(const bf16x8*)((BBUF) + brow_b + 2*2048 + col1);              \
      bfr[6] = *(const bf16x8*)((BBUF) + brow_b + 3*2048 + col0);              \
      bfr[7] = *(const bf16x8*)((BBUF) + brow_b + 3*2048 + col1);              \
    }                                                                          \
    S0; S1;                                                                    \
    asm volatile("" ::: "memory");                                             \
    __builtin_amdgcn_s_barrier();                                              \
    asm volatile("" ::: "memory");                                             \
    __builtin_amdgcn_sched_barrier(0);                                         \
    __builtin_amdgcn_s_setprio(1);                                             \
    acc[2*(Q)][0]   = __builtin_amdgcn_mfma_f32_16x16x32_bf16(a00, bfr[0], acc[2*(Q)][0], 0, 0, 0);   \
    acc[2*(Q)][1]   = __builtin_amdgcn_mfma_f32_16x16x32_bf16(a00, bfr[2], acc[2*(Q)][1], 0, 0, 0);   \
    acc[2*(Q)][2]   = __builtin_amdgcn_mfma_f32_16x16x32_bf16(a00, bfr[4], acc[2*(Q)][2], 0, 0, 0);   \
    acc[2*(Q)][3]   = __builtin_amdgcn_mfma_f32_16x16x32_bf16(a00, bfr[6], acc[2*(Q)][3], 0, 0, 0);   \
    acc[2*(Q)+1][0] = __builtin_amdgcn_mfma_f32_16x16x32_bf16(a10, bfr[0], acc[2*(Q)+1][0], 0, 0, 0); \
    acc[2*(Q)+1][1] = __builtin_amdgcn_mfma_f32_16x16x32_bf16(a10, bfr[2], acc[2*(Q)+1][1], 0, 0, 0); \
    acc[2*(Q)+1][2] = __builtin_amdgcn_mfma_f32_16x16x32_bf16(a10, bfr[4], acc[2*(Q)+1][2], 0, 0, 0); \
    acc[2*(Q)+1][3] = __builtin_amdgcn_mfma_f32_16x16x32_bf16(a10, bfr[6], acc[2*(Q)+1][3], 0, 0, 0); \
    acc[2*(Q)][0]   = __builtin_amdgcn_mfma_f32_16x16x32_bf16(a01, bfr[1], acc[2*(Q)][0], 0, 0, 0);   \
    acc[2*(Q)][1]   = __builtin_amdgcn_mfma_f32_16x16x32_bf16(a01, bfr[3], acc[2*(Q)][1], 0, 0, 0);   \
    acc[2*(Q)][2]   = __builtin_amdgcn_mfma_f32_16x16x32_bf16(a01, bfr[5], acc[2*(Q)][2], 0, 0, 0);   \
    acc[2*(Q)][3]   = __builtin_amdgcn_mfma_f32_16x16x32_bf16(a01, bfr[7], acc[2*(Q)][3], 0, 0, 0);   \
    acc[2*(Q)+1][0] = __builtin_amdgcn_mfma_f32_16x16x32_bf16(a11, bfr[1], acc[2*(Q)+1][0], 0, 0, 0); \
    acc[2*(Q)+1][1] = __builtin_amdgcn_mfma_f32_16x16x32_bf16(a11, bfr[3], acc[2*(Q)+1][1], 0, 0, 0); \
    acc[2*(Q)+1][2] = __builtin_amdgcn_mfma_f32_16x16x32_bf16(a11, bfr[5], acc[2*(Q)+1][2], 0, 0, 0); \
    acc[2*(Q)+1][3] = __builtin_amdgcn_mfma_f32_16x16x32_bf16(a11, bfr[7], acc[2*(Q)+1][3], 0, 0, 0); \
    __builtin_amdgcn_s_setprio(0);                                             \
    VW;                                                                        \
    asm volatile("" ::: "memory");                                             \
    __builtin_amdgcn_s_barrier();                                              \
    asm volatile("" ::: "memory");                                             \
    __builtin_amdgcn_sched_barrier(0);                                         \
  }

template <bool OUTBF>
__global__ __launch_bounds__(512, 2) void gemm256(const u16* __restrict__ A,
                                                  const u16* __restrict__ B,
                                                  void* __restrict__ C,
                                                  int M, int N, int K, int tx) {
  __shared__ __align__(16) char lds[131072];
  const int tid = threadIdx.x;
  const int lane = tid & 63, wave = tid >> 6;
  const int fr = lane & 15, fq = lane >> 4;
  const int wm = wave >> 2, wn = wave & 3;

  const int nwg = gridDim.x;
  const int qq = nwg >> 3, r8 = nwg & 7;
  const int orig = blockIdx.x;
  const int xcd = orig & 7, idx = orig >> 3;
  const int wg = (xcd < r8) ? (xcd * (qq + 1) + idx)
                            : (r8 * (qq + 1) + (xcd - r8) * qq + idx);
  const int bx = wg % tx, by = wg / tx;
  const int aRow0 = by << 8, bCol0 = bx << 8;

  const size_t K2 = (size_t)K * 2;
  const int KT = K >> 6;
  const int NIT = KT >> 1;

  const int trow = tid >> 3;
  const int scol = ((tid & 7) * 16) ^ ((trow & 7) << 4);
  const char* Ab = (const char*)A + (size_t)(aRow0 + trow) * K2 + scol;
  const char* Bb = (const char*)B + (size_t)(bCol0 + trow) * K2 + scol;

  char* a0 = lds;
  char* b0 = lds + 32768;
  char* a1 = lds + 65536;
  char* b1 = lds + 98304;

#define STG_A(dst, gk, ra) gload_lds16(Ab + (size_t)(ra) * K2 + (size_t)(gk) * 128, (dst) + ((ra) << 7) + tid * 16)
#define STG_B(dst, gk, ra) gload_lds16(Bb + (size_t)(ra) * K2 + (size_t)(gk) * 128, (dst) + ((ra) << 7) + tid * 16)

  const int swzr = (fr & 7) << 4;
  const int col0 = (fq * 16) ^ swzr;
  const int col1 = (64 + fq * 16) ^ swzr;
  const int arow_b = (wm * 128 + fr) * 128;
  const int brow_b = (wn * 64 + fr) * 128;

  const f32x4 z4 = {0.f, 0.f, 0.f, 0.f};
  f32x4 acc[8][4];
#pragma unroll
  for (int i = 0; i < 8; i++)
#pragma unroll
    for (int j = 0; j < 4; j++) acc[i][j] = z4;
  bf16x8 bfr[8];

  STG_B(b0, 0, 0);   STG_B(b0, 0, 64);
  STG_B(b0, 0, 128); STG_B(b0, 0, 192);
  STG_A(a0, 0, 0);   STG_A(a0, 0, 128);
  STG_A(a0, 0, 64);  STG_A(a0, 0, 192);
  STG_B(b1, 1, 0);   STG_B(b1, 1, 64);
  STG_B(b1, 1, 128); STG_B(b1, 1, 192);
  STG_A(a1, 1, 0);   STG_A(a1, 1, 128);
  VMW6;
  asm volatile("" ::: "memory");
  __builtin_amdgcn_s_barrier();
  asm volatile("" ::: "memory");
  __builtin_amdgcn_sched_barrier(0);

  for (int it = 0; it < NIT; ++it) {
    const int G = it << 1;
    const int g2 = (G + 2 < KT) ? G + 2 : KT - 1;
    const int g3 = (G + 3 < KT) ? G + 3 : KT - 1;
    PHASE(a0, b0, 0, STG_A(a1, G + 1, 64), STG_A(a1, G + 1, 192), NOP2);
    PHASE(a0, b0, 1, STG_B(b0, g2, 0),     STG_B(b0, g2, 64),     NOP2);
    PHASE(a0, b0, 2, STG_B(b0, g2, 128),   STG_B(b0, g2, 192),    NOP2);
    PHASE(a0, b0, 3, STG_A(a0, g2, 0),     STG_A(a0, g2, 128),    VMW6);
    PHASE(a1, b1, 0, STG_A(a0, g2, 64),    STG_A(a0, g2, 192),    NOP2);
    PHASE(a1, b1, 1, STG_B(b1, g3, 0),     STG_B(b1, g3, 64),     NOP2);
    PHASE(a1, b1, 2, STG_B(b1, g3, 128),   STG_B(b1, g3, 192),    NOP2);
    PHASE(a1, b1, 3, STG_A(a1, g3, 0),     STG_A(a1, g3, 128),    VMW6);
  }

#pragma unroll
  for (int mi = 0; mi < 8; mi++)
#pragma unroll
    for (int ni = 0; ni < 4; ni++)
#pragma unroll
      for (int r2 = 0; r2 < 4; r2++) {
        int row = aRow0 + wm * 128 + mi * 16 + fq * 4 + r2;
        int col = bCol0 + wn * 64 + ni * 16 + fr;
        if (OUTBF)
          ((u16*)C)[(size_t)row * N + col] = f2bf(acc[mi][ni][r2]);
        else
          ((float*)C)[(size_t)row * N + col] = acc[mi][ni][r2];
      }
}

// ---------------- flash attention (causal, GQA) ---------------------------
// Uniform-work pairing: block bx handles q-subtiles (31-bx, bx) as two
// phases -> every block does exactly 33 KV-tile units (kills the triangle
// tail that pinned occupancy at 19.6%). Body = round-4 structure: 4 waves x
// 16 q-rows, KV tile 64, single-buffer 2-barrier loop, swapped QK^T.
// VALU trims: diagonal-only mask; exp2-domain softmax (fma+exp2, defer
// threshold 90.51 raw = e^8). LDS 40KB -> 4 blocks/CU.
__global__ __launch_bounds__(256, 4) void attn_fwd(const u16* __restrict__ QKV,
                                                   u16* __restrict__ Ob) {
  const int bxp = blockIdx.x;  // 0..15
  const int h = blockIdx.y, b = blockIdx.z;
  const int hkv = h / REP;
  const int tid = threadIdx.x, lane = tid & 63, wave = tid >> 6;
  const int fr = lane & 15, fq = lane >> 4;

  __shared__ u16 Ks[64 * 128];
  __shared__ u16 Vt[128 * 64];   // transposed: [d][kv]
  __shared__ u16 Ps[4 * 16 * 64];

  int kro[4], kco[4];
#pragma unroll
  for (int rd = 0; rd < 4; rd++) {
    int o = rd * 4096 + wave * 1024 + lane * 16;
    kro[rd] = o >> 8;
    kco[rd] = ((o & 255) ^ ((kro[rd] & 7) << 4)) >> 1;
  }
  const int vp = tid & 31;  // kv pair index (rows 2vp, 2vp+1)
  const int vc = tid >> 5;  // d chunk (16 wide), 0..7

  const float Cs = 0.12751741f;  // SCALE * log2(e)
  const f32x4 z4 = {0.f, 0.f, 0.f, 0.f};

  for (int ph = 0; ph < 2; ph++) {
    const int st = ph ? bxp : 31 - bxp;

    // Q fragments straight from global (wave-private q-rows)
    const int qr = wave * 16 + fr;
    const size_t qrow = (size_t)(b * SEQ + st * 64 + qr) * QSTR + h * HD;
    bf16x8 qf[4];
#pragma unroll
    for (int kc = 0; kc < 4; kc++)
      qf[kc] = *(const bf16x8*)(QKV + qrow + kc * 32 + fq * 8);

    float mr = -1e30f;   // running row max (RAW score units)
    float mC = 0.f;      // mr * Cs (set on first defer-trigger, j=0 always fires)
    float lp = 0.f;      // per-lane PARTIAL row sum
    f32x4 ov[8];
#pragma unroll
    for (int i = 0; i < 8; i++) ov[i] = z4;

    for (int j = 0; j <= st; j++) {
      const size_t base = (size_t)(b * SEQ + j * 64) * QSTR;
      const size_t kbase = base + KOFF + hkv * HD;
      const size_t vbase = base + VOFF + hkv * HD;
#pragma unroll
      for (int rd = 0; rd < 4; rd++)
        gload_lds16(QKV + kbase + (size_t)kro[rd] * QSTR + kco[rd],
                    (char*)Ks + (rd * 4096 + wave * 1024));
      {  // V transpose: rows 2vp/2vp+1, 16 d-columns each (32B loads)
        const u16* v0 = QKV + vbase + (size_t)(2 * vp) * QSTR + vc * 16;
        u16x16 ra = *(const u16x16*)v0;
        u16x16 rb = *(const u16x16*)(v0 + QSTR);
#pragma unroll
        for (int i = 0; i < 16; i++) {
          int d = vc * 16 + i;
          u32 val = (u32)ra[i] | ((u32)rb[i] << 16);
          *(u32*)((char*)Vt + d * 128 + ((vp * 4) ^ ((d & 7) << 4))) = val;
        }
      }
      __syncthreads();

      // S = K Q^T (swapped): sc[ni][r] = S_raw[k=j*64+ni*16+fq*4+r][q=wave*16+fr]
      f32x4 sc[4];
#pragma unroll
      for (int ni = 0; ni < 4; ni++) sc[ni] = z4;
#pragma unroll
      for (int kc = 0; kc < 4; kc++) {
#pragma unroll
        for (int ni = 0; ni < 4; ni++) {
          int kr = ni * 16 + fr;
          bf16x8 bk = *(const bf16x8*)((const char*)Ks + kr * 256 +
                                       ((kc * 64 + fq * 16) ^ ((kr & 7) << 4)));
          sc[ni] = __builtin_amdgcn_mfma_f32_16x16x32_bf16(bk, qf[kc], sc[ni], 0, 0, 0);
        }
      }

      // causal mask: only the diagonal tile needs it
      if (j == st) {
        const int rowg = st * 64 + wave * 16 + fr;
#pragma unroll
        for (int ni = 0; ni < 4; ni++)
#pragma unroll
          for (int r = 0; r < 4; r++) {
            int colg = j * 64 + ni * 16 + fq * 4 + r;
            if (colg > rowg) sc[ni][r] = -1e30f;
          }
      }

      // tile max (raw units): in-register tree + 2 cross-lane steps
      float pmax;
      {
        f32x4 m4 = sc[0];
#pragma unroll
        for (int ni = 1; ni < 4; ni++)
#pragma unroll
          for (int r = 0; r < 4; r++) m4[r] = fmaxf(m4[r], sc[ni][r]);
        pmax = fmaxf(fmaxf(m4[0], m4[1]), fmaxf(m4[2], m4[3]));
        pmax = fmaxf(pmax, __shfl_xor(pmax, 16));
        pmax = fmaxf(pmax, __shfl_xor(pmax, 32));
      }

      // defer-max: rescale only when tile max beats running max by > 8/SCALE
      if (__any(pmax > mr + 90.509668f)) {
        float mnew = fmaxf(mr, pmax);
        float sf = EXP2((mr - mnew) * Cs);
        mr = mnew;
        mC = mr * Cs;
        lp *= sf;
#pragma unroll
        for (int r = 0; r < 4; r++) {
          float sr = __shfl(sf, fq * 4 + r);
#pragma unroll
          for (int n2 = 0; n2 < 8; n2++) ov[n2][r] *= sr;
        }
      }

      // p = exp2(s*Cs - mC); partial-sum; pack bf16; P -> LDS (8 u32 stores)
      {
        char* pb = (char*)Ps + wave * 2048 + fr * 128;
        const int swz = (fr & 7) << 4;
        float lad = 0.f;
#pragma unroll
        for (int ni = 0; ni < 4; ni++) {
          float p0 = EXP2(fmaf(sc[ni][0], Cs, -mC));
          float p1 = EXP2(fmaf(sc[ni][1], Cs, -mC));
          float p2 = EXP2(fmaf(sc[ni][2], Cs, -mC));
          float p3 = EXP2(fmaf(sc[ni][3], Cs, -mC));
          lad += (p0 + p1) + (p2 + p3);
          bf16x2 w0 = {(__bf16)p0, (__bf16)p1};
          bf16x2 w1 = {(__bf16)p2, (__bf16)p3};
          int kb = ni * 32 + fq * 8;
          *(u32*)(pb + (kb ^ swz)) = __builtin_bit_cast(u32, w0);
          *(u32*)(pb + ((kb + 4) ^ swz)) = __builtin_bit_cast(u32, w1);
        }
        lp += lad;
      }

      // O += P V (16 MFMA / wave); ov rows q = fq*4+r, cols d = n2*16+fr
#pragma unroll
      for (int kc = 0; kc < 2; kc++) {
        bf16x8 ap = *(const bf16x8*)((const char*)Ps + wave * 2048 + fr * 128 +
                                     ((kc * 64 + fq * 16) ^ ((fr & 7) << 4)));
#pragma unroll
        for (int n2 = 0; n2 < 8; n2++) {
          int vd = n2 * 16 + fr;
          bf16x8 bv = *(const bf16x8*)((const char*)Vt + vd * 128 +
                                       ((kc * 64 + fq * 16) ^ ((vd & 7) << 4)));
          ov[n2] = __builtin_amdgcn_mfma_f32_16x16x32_bf16(ap, bv, ov[n2], 0, 0, 0);
        }
      }
      __syncthreads();
    }

    // final row-sum reduce + normalize + store (per phase)
    float ls = lp;
    ls += __shfl_xor(ls, 16);
    ls += __shfl_xor(ls, 32);
#pragma unroll
    for (int r = 0; r < 4; r++) {
      float lr = __shfl(ls, fq * 4 + r);
      float inv = 1.0f / lr;
      size_t rowg = (size_t)(b * SEQ + st * 64 + wave * 16 + fq * 4 + r) * HIDDEN + h * HD;
#pragma unroll
      for (int n2 = 0; n2 < 8; n2++)
        Ob[rowg + n2 * 16 + fr] = f2bf(ov[n2][r] * inv);
    }
  }
}

// ---------------- launch --------------------------------------------------
extern "C" void kernel_launch(void* const* d_in, const int* in_sizes, int n_in,
                              void* d_out, int out_size, void* d_ws, size_t ws_size,
                              hipStream_t stream) {
  const float* hidden = (const float*)d_in[0];
  // d_in[1] = attention_mask: exactly the causal mask -> applied analytically
  const int* pos = (const int*)d_in[2];
  const float* Wq = (const float*)d_in[3];
  const float* Wk = (const float*)d_in[4];
  const float* Wv = (const float*)d_in[5];
  const float* Wo = (const float*)d_in[6];
  float* out = (float*)d_out;
  char* ws = (char*)d_ws;

  // workspace layout (bytes), total 120 MiB
  u16* wqkv = (u16*)(ws + 0);         // [4608][3584] bf16
  u16* wob  = (u16*)(ws + 33030144);  // [3584][3584]
  u16* hb   = (u16*)(ws + 58720256);  // [4096][3584] hidden bf16; reused as attn out
  u16* attnb = hb;
  float2* tab = (float2*)(ws + 58720256);  // 1MB sincos table: lives in the dead
                                           // hb window (after QKV gemm, before attn)
  u16* qkv  = (u16*)(ws + 88080384);  // [4096][4608] fused Q|K|V

  cvt_all<<<21504, 256, 0, stream>>>(hidden, Wq, Wk, Wv, Wo, hb, wqkv, wob);

  // fused QKV projection: [4096, 4608] = hb[4096,3584] @ wqkv^T
  gemm256<true><<<288, 512, 0, stream>>>(hb, wqkv, qkv, 4096, QSTR, HIDDEN, 18);

  // RoPE: build table (hb now dead), then apply to Q+K heads
  rope_tab<<<512, 256, 0, stream>>>(tab);
  rope_ip8<<<4096, 256, 0, stream>>>(qkv, pos, tab);

  attn_fwd<<<dim3(16, NH, NB), 256, 0, stream>>>(qkv, attnb);

  gemm256<false><<<224, 512, 0, stream>>>(attnb, wob, out, 4096, HIDDEN, HIDDEN, 14);
}

// Round 14
// 439.760 us; speedup vs baseline: 1.0017x; 1.0013x over previous
//
#include <hip/hip_runtime.h>
#include <cstdint>
#include <cstddef>

#define HIDDEN 3584
#define NH 28
#define NKV 4
#define HD 128
#define SEQ 2048
#define NB 2
#define REP (NH / NKV)   // 7
#define QSTR 4608        // fused qkv row stride (3584 + 512 + 512)
#define KOFF 3584
#define VOFF 4096

typedef unsigned short u16;
typedef unsigned int u32;
typedef __bf16 bf16x8 __attribute__((ext_vector_type(8)));
typedef __bf16 bf16x2 __attribute__((ext_vector_type(2)));
typedef float f32x4 __attribute__((ext_vector_type(4)));
typedef u16 u16x8 __attribute__((ext_vector_type(8)));
typedef u16 u16x16 __attribute__((ext_vector_type(16)));

#if __has_builtin(__builtin_amdgcn_exp2f)
#define EXP2(x) __builtin_amdgcn_exp2f(x)
#else
#define EXP2(x) exp2f(x)
#endif

__device__ __forceinline__ u16 f2bf(float f) {
  u32 u = __builtin_bit_cast(u32, f);
  u = (u + 0x7fffu + ((u >> 16) & 1u)) >> 16;
  return (u16)u;
}
__device__ __forceinline__ float bf2f(u16 h) {
  u32 u = ((u32)h) << 16;
  return __builtin_bit_cast(float, u);
}

__device__ __forceinline__ void gload_lds16(const void* g, void* l) {
  __builtin_amdgcn_global_load_lds(
      (__attribute__((address_space(1))) void*)(const_cast<void*>(g)),
      (__attribute__((address_space(3))) void*)(l), 16, 0, 0);
}

// ---------------- fused fp32 -> bf16 conversion (5 tensors, one grid) -----
__global__ __launch_bounds__(256) void cvt_all(const float* __restrict__ h,
                                               const float* __restrict__ wq,
                                               const float* __restrict__ wk,
                                               const float* __restrict__ wv,
                                               const float* __restrict__ wo,
                                               u16* __restrict__ hb,
                                               u16* __restrict__ wqkv,
                                               u16* __restrict__ wob) {
  int bx = blockIdx.x;
  const float* s; u16* d; int lb;
  if (bx < 7168)       { s = h;  d = hb;   lb = bx; }
  else if (bx < 13440) { s = wq; d = wqkv; lb = bx - 7168; }
  else if (bx < 14336) { s = wk; d = wqkv + (size_t)KOFF * HIDDEN; lb = bx - 13440; }
  else if (bx < 15232) { s = wv; d = wqkv + (size_t)VOFF * HIDDEN; lb = bx - 14336; }
  else                 { s = wo; d = wob;  lb = bx - 15232; }
  size_t i = ((size_t)lb * 256 + threadIdx.x) * 8;
  float4 a = *(const float4*)(s + i);
  float4 b = *(const float4*)(s + i + 4);
  u32 o0 = f2bf(a.x) | ((u32)f2bf(a.y) << 16);
  u32 o1 = f2bf(a.z) | ((u32)f2bf(a.w) << 16);
  u32 o2 = f2bf(b.x) | ((u32)f2bf(b.y) << 16);
  u32 o3 = f2bf(b.z) | ((u32)f2bf(b.w) << 16);
  uint4 o; o.x = o0; o.y = o1; o.z = o2; o.w = o3;
  *(uint4*)(d + i) = o;
}

// ---------------- RoPE: sincos table (2048 x 64) --------------------------
__global__ __launch_bounds__(256) void rope_tab(float2* __restrict__ tab) {
  int i = blockIdx.x * 256 + threadIdx.x;   // 131072
  int d = i & 63;
  float p = (float)(i >> 6);
  float freq = exp2f(-(float)d * (19.93156856932417f / 64.0f));
  float sv, cv;
  sincosf(p * freq, &sv, &cv);
  tab[i] = make_float2(cv, sv);
}

// ---------------- RoPE in-place, table-driven, bf16x8 vectorized ----------
// thread = (row, head, d8-group of 8): pairs (d, d+64) within head.
__global__ __launch_bounds__(256) void rope_ip8(u16* __restrict__ X,
                                                const int* __restrict__ pos,
                                                const float2* __restrict__ tab) {
  int i = blockIdx.x * 256 + threadIdx.x;
  int row = i >> 8;           // 256 groups per row (32 heads x 8)
  int g = i & 255;
  int head = g >> 3, d0 = (g & 7) * 8;
  u16* px = X + (size_t)row * QSTR + head * 128 + d0;
  u16x8 a = *(const u16x8*)px;
  u16x8 b = *(const u16x8*)(px + 64);
  const float2* t = tab + (pos[row] << 6) + d0;
#pragma unroll
  for (int e = 0; e < 8; e++) {
    float2 cs = t[e];
    float x1 = bf2f(a[e]), x2 = bf2f(b[e]);
    a[e] = f2bf(x1 * cs.x - x2 * cs.y);
    b[e] = f2bf(x2 * cs.x + x1 * cs.y);
  }
  *(u16x8*)px = a;
  *(u16x8*)(px + 64) = b;
}

// ---------------- bf16 GEMM 256x256, BK=64, 8-phase pipeline --------------
#define VMW6 asm volatile("s_waitcnt vmcnt(6)" ::: "memory")
#define NOP2 ((void)0)

#define PHASE(ABUF, BBUF, Q, S0, S1, VW)                                       \
  {                                                                            \
    bf16x8 a00 = *(const bf16x8*)((ABUF) + arow_b + (2*(Q))*2048 + col0);      \
    bf16x8 a01 = *(const bf16x8*)((ABUF) + arow_b + (2*(Q))*2048 + col1);      \
    bf16x8 a10 = *(const bf16x8*)((ABUF) + arow_b + (2*(Q)+1)*2048 + col0);    \
    bf16x8 a11 = *(const bf16x8*)((ABUF) + arow_b + (2*(Q)+1)*2048 + col1);    \
    if ((Q) == 0) {                                                            \
      bfr[0] = *(const bf16x8*)((BBUF) + brow_b + 0*2048 + col0);              \
      bfr[1] = *(const bf16x8*)((BBUF) + brow_b + 0*2048 + col1);              \
      bfr[2] = *(const bf16x8*)((BBUF) + brow_b + 1*2048 + col0);              \
      bfr[3] = *(const bf16x8*)((BBUF) + brow_b + 1*2048 + col1);              \
      bfr[4] = *(const bf16x8*)((BBUF) + brow_b + 2*2048 + col0);              \
      bfr[5] = *(const bf16x8*)((BBUF) + brow_b + 2*2048 + col1);              \
      bfr[6] = *(const bf16x8*)((BBUF) + brow_b + 3*2048 + col0);              \
      bfr[7] = *(const bf16x8*)((BBUF) + brow_b + 3*2048 + col1);              \
    }                                                                          \
    S0; S1;                                                                    \
    asm volatile("" ::: "memory");                                             \
    __builtin_amdgcn_s_barrier();                                              \
    asm volatile("" ::: "memory");                                             \
    __builtin_amdgcn_sched_barrier(0);                                         \
    __builtin_amdgcn_s_setprio(1);                                             \
    acc[2*(Q)][0]   = __builtin_amdgcn_mfma_f32_16x16x32_bf16(a00, bfr[0], acc[2*(Q)][0], 0, 0, 0);   \
    acc[2*(Q)][1]   = __builtin_amdgcn_mfma_f32_16x16x32_bf16(a00, bfr[2], acc[2*(Q)][1], 0, 0, 0);   \
    acc[2*(Q)][2]   = __builtin_amdgcn_mfma_f32_16x16x32_bf16(a00, bfr[4], acc[2*(Q)][2], 0, 0, 0);   \
    acc[2*(Q)][3]   = __builtin_amdgcn_mfma_f32_16x16x32_bf16(a00, bfr[6], acc[2*(Q)][3], 0, 0, 0);   \
    acc[2*(Q)+1][0] = __builtin_amdgcn_mfma_f32_16x16x32_bf16(a10, bfr[0], acc[2*(Q)+1][0], 0, 0, 0); \
    acc[2*(Q)+1][1] = __builtin_amdgcn_mfma_f32_16x16x32_bf16(a10, bfr[2], acc[2*(Q)+1][1], 0, 0, 0); \
    acc[2*(Q)+1][2] = __builtin_amdgcn_mfma_f32_16x16x32_bf16(a10, bfr[4], acc[2*(Q)+1][2], 0, 0, 0); \
    acc[2*(Q)+1][3] = __builtin_amdgcn_mfma_f32_16x16x32_bf16(a10, bfr[6], acc[2*(Q)+1][3], 0, 0, 0); \
    acc[2*(Q)][0]   = __builtin_amdgcn_mfma_f32_16x16x32_bf16(a01, bfr[1], acc[2*(Q)][0], 0, 0, 0);   \
    acc[2*(Q)][1]   = __builtin_amdgcn_mfma_f32_16x16x32_bf16(a01, bfr[3], acc[2*(Q)][1], 0, 0, 0);   \
    acc[2*(Q)][2]   = __builtin_amdgcn_mfma_f32_16x16x32_bf16(a01, bfr[5], acc[2*(Q)][2], 0, 0, 0);   \
    acc[2*(Q)][3]   = __builtin_amdgcn_mfma_f32_16x16x32_bf16(a01, bfr[7], acc[2*(Q)][3], 0, 0, 0);   \
    acc[2*(Q)+1][0] = __builtin_amdgcn_mfma_f32_16x16x32_bf16(a11, bfr[1], acc[2*(Q)+1][0], 0, 0, 0); \
    acc[2*(Q)+1][1] = __builtin_amdgcn_mfma_f32_16x16x32_bf16(a11, bfr[3], acc[2*(Q)+1][1], 0, 0, 0); \
    acc[2*(Q)+1][2] = __builtin_amdgcn_mfma_f32_16x16x32_bf16(a11, bfr[5], acc[2*(Q)+1][2], 0, 0, 0); \
    acc[2*(Q)+1][3] = __builtin_amdgcn_mfma_f32_16x16x32_bf16(a11, bfr[7], acc[2*(Q)+1][3], 0, 0, 0); \
    __builtin_amdgcn_s_setprio(0);                                             \
    VW;                                                                        \
    asm volatile("" ::: "memory");                                             \
    __builtin_amdgcn_s_barrier();                                              \
    asm volatile("" ::: "memory");                                             \
    __builtin_amdgcn_sched_barrier(0);                                         \
  }

template <bool OUTBF>
__global__ __launch_bounds__(512, 2) void gemm256(const u16* __restrict__ A,
                                                  const u16* __restrict__ B,
                                                  void* __restrict__ C,
                                                  int M, int N, int K, int tx) {
  __shared__ __align__(16) char lds[131072];
  const int tid = threadIdx.x;
  const int lane = tid & 63, wave = tid >> 6;
  const int fr = lane & 15, fq = lane >> 4;
  const int wm = wave >> 2, wn = wave & 3;

  const int nwg = gridDim.x;
  const int qq = nwg >> 3, r8 = nwg & 7;
  const int orig = blockIdx.x;
  const int xcd = orig & 7, idx = orig >> 3;
  const int wg = (xcd < r8) ? (xcd * (qq + 1) + idx)
                            : (r8 * (qq + 1) + (xcd - r8) * qq + idx);
  const int bx = wg % tx, by = wg / tx;
  const int aRow0 = by << 8, bCol0 = bx << 8;

  const size_t K2 = (size_t)K * 2;
  const int KT = K >> 6;
  const int NIT = KT >> 1;

  const int trow = tid >> 3;
  const int scol = ((tid & 7) * 16) ^ ((trow & 7) << 4);
  const char* Ab = (const char*)A + (size_t)(aRow0 + trow) * K2 + scol;
  const char* Bb = (const char*)B + (size_t)(bCol0 + trow) * K2 + scol;

  char* a0 = lds;
  char* b0 = lds + 32768;
  char* a1 = lds + 65536;
  char* b1 = lds + 98304;

#define STG_A(dst, gk, ra) gload_lds16(Ab + (size_t)(ra) * K2 + (size_t)(gk) * 128, (dst) + ((ra) << 7) + tid * 16)
#define STG_B(dst, gk, ra) gload_lds16(Bb + (size_t)(ra) * K2 + (size_t)(gk) * 128, (dst) + ((ra) << 7) + tid * 16)

  const int swzr = (fr & 7) << 4;
  const int col0 = (fq * 16) ^ swzr;
  const int col1 = (64 + fq * 16) ^ swzr;
  const int arow_b = (wm * 128 + fr) * 128;
  const int brow_b = (wn * 64 + fr) * 128;

  const f32x4 z4 = {0.f, 0.f, 0.f, 0.f};
  f32x4 acc[8][4];
#pragma unroll
  for (int i = 0; i < 8; i++)
#pragma unroll
    for (int j = 0; j < 4; j++) acc[i][j] = z4;
  bf16x8 bfr[8];

  STG_B(b0, 0, 0);   STG_B(b0, 0, 64);
  STG_B(b0, 0, 128); STG_B(b0, 0, 192);
  STG_A(a0, 0, 0);   STG_A(a0, 0, 128);
  STG_A(a0, 0, 64);  STG_A(a0, 0, 192);
  STG_B(b1, 1, 0);   STG_B(b1, 1, 64);
  STG_B(b1, 1, 128); STG_B(b1, 1, 192);
  STG_A(a1, 1, 0);   STG_A(a1, 1, 128);
  VMW6;
  asm volatile("" ::: "memory");
  __builtin_amdgcn_s_barrier();
  asm volatile("" ::: "memory");
  __builtin_amdgcn_sched_barrier(0);

  for (int it = 0; it < NIT; ++it) {
    const int G = it << 1;
    const int g2 = (G + 2 < KT) ? G + 2 : KT - 1;
    const int g3 = (G + 3 < KT) ? G + 3 : KT - 1;
    PHASE(a0, b0, 0, STG_A(a1, G + 1, 64), STG_A(a1, G + 1, 192), NOP2);
    PHASE(a0, b0, 1, STG_B(b0, g2, 0),     STG_B(b0, g2, 64),     NOP2);
    PHASE(a0, b0, 2, STG_B(b0, g2, 128),   STG_B(b0, g2, 192),    NOP2);
    PHASE(a0, b0, 3, STG_A(a0, g2, 0),     STG_A(a0, g2, 128),    VMW6);
    PHASE(a1, b1, 0, STG_A(a0, g2, 64),    STG_A(a0, g2, 192),    NOP2);
    PHASE(a1, b1, 1, STG_B(b1, g3, 0),     STG_B(b1, g3, 64),     NOP2);
    PHASE(a1, b1, 2, STG_B(b1, g3, 128),   STG_B(b1, g3, 192),    NOP2);
    PHASE(a1, b1, 3, STG_A(a1, g3, 0),     STG_A(a1, g3, 128),    VMW6);
  }

#pragma unroll
  for (int mi = 0; mi < 8; mi++)
#pragma unroll
    for (int ni = 0; ni < 4; ni++)
#pragma unroll
      for (int r2 = 0; r2 < 4; r2++) {
        int row = aRow0 + wm * 128 + mi * 16 + fq * 4 + r2;
        int col = bCol0 + wn * 64 + ni * 16 + fr;
        if (OUTBF)
          ((u16*)C)[(size_t)row * N + col] = f2bf(acc[mi][ni][r2]);
        else
          ((float*)C)[(size_t)row * N + col] = acc[mi][ni][r2];
      }
}

// ---------------- flash attention (causal, GQA) ---------------------------
// Uniform-work pairing: block bx handles q-subtiles (31-bx, bx) as two
// phases -> every block does exactly 33 KV-tile units (kills the triangle
// tail that pinned occupancy at 19.6%). Body = round-4 structure: 4 waves x
// 16 q-rows, KV tile 64, single-buffer 2-barrier loop, swapped QK^T.
// VALU trims: diagonal-only mask; exp2-domain softmax (fma+exp2, defer
// threshold 90.51 raw = e^8). LDS 40KB -> 4 blocks/CU.
__global__ __launch_bounds__(256, 4) void attn_fwd(const u16* __restrict__ QKV,
                                                   u16* __restrict__ Ob) {
  const int bxp = blockIdx.x;  // 0..15
  const int h = blockIdx.y, b = blockIdx.z;
  const int hkv = h / REP;
  const int tid = threadIdx.x, lane = tid & 63, wave = tid >> 6;
  const int fr = lane & 15, fq = lane >> 4;

  __shared__ u16 Ks[64 * 128];
  __shared__ u16 Vt[128 * 64];   // transposed: [d][kv]
  __shared__ u16 Ps[4 * 16 * 64];

  int kro[4], kco[4];
#pragma unroll
  for (int rd = 0; rd < 4; rd++) {
    int o = rd * 4096 + wave * 1024 + lane * 16;
    kro[rd] = o >> 8;
    kco[rd] = ((o & 255) ^ ((kro[rd] & 7) << 4)) >> 1;
  }
  const int vp = tid & 31;  // kv pair index (rows 2vp, 2vp+1)
  const int vc = tid >> 5;  // d chunk (16 wide), 0..7

  const float Cs = 0.12751741f;  // SCALE * log2(e)
  const f32x4 z4 = {0.f, 0.f, 0.f, 0.f};

  for (int ph = 0; ph < 2; ph++) {
    const int st = ph ? bxp : 31 - bxp;

    // Q fragments straight from global (wave-private q-rows)
    const int qr = wave * 16 + fr;
    const size_t qrow = (size_t)(b * SEQ + st * 64 + qr) * QSTR + h * HD;
    bf16x8 qf[4];
#pragma unroll
    for (int kc = 0; kc < 4; kc++)
      qf[kc] = *(const bf16x8*)(QKV + qrow + kc * 32 + fq * 8);

    float mr = -1e30f;   // running row max (RAW score units)
    float mC = 0.f;      // mr * Cs (set on first defer-trigger, j=0 always fires)
    float lp = 0.f;      // per-lane PARTIAL row sum
    f32x4 ov[8];
#pragma unroll
    for (int i = 0; i < 8; i++) ov[i] = z4;

    for (int j = 0; j <= st; j++) {
      const size_t base = (size_t)(b * SEQ + j * 64) * QSTR;
      const size_t kbase = base + KOFF + hkv * HD;
      const size_t vbase = base + VOFF + hkv * HD;
#pragma unroll
      for (int rd = 0; rd < 4; rd++)
        gload_lds16(QKV + kbase + (size_t)kro[rd] * QSTR + kco[rd],
                    (char*)Ks + (rd * 4096 + wave * 1024));
      {  // V transpose: rows 2vp/2vp+1, 16 d-columns each (32B loads)
        const u16* v0 = QKV + vbase + (size_t)(2 * vp) * QSTR + vc * 16;
        u16x16 ra = *(const u16x16*)v0;
        u16x16 rb = *(const u16x16*)(v0 + QSTR);
#pragma unroll
        for (int i = 0; i < 16; i++) {
          int d = vc * 16 + i;
          u32 val = (u32)ra[i] | ((u32)rb[i] << 16);
          *(u32*)((char*)Vt + d * 128 + ((vp * 4) ^ ((d & 7) << 4))) = val;
        }
      }
      __syncthreads();

      // S = K Q^T (swapped): sc[ni][r] = S_raw[k=j*64+ni*16+fq*4+r][q=wave*16+fr]
      f32x4 sc[4];
#pragma unroll
      for (int ni = 0; ni < 4; ni++) sc[ni] = z4;
#pragma unroll
      for (int kc = 0; kc < 4; kc++) {
#pragma unroll
        for (int ni = 0; ni < 4; ni++) {
          int kr = ni * 16 + fr;
          bf16x8 bk = *(const bf16x8*)((const char*)Ks + kr * 256 +
                                       ((kc * 64 + fq * 16) ^ ((kr & 7) << 4)));
          sc[ni] = __builtin_amdgcn_mfma_f32_16x16x32_bf16(bk, qf[kc], sc[ni], 0, 0, 0);
        }
      }

      // causal mask: only the diagonal tile needs it
      if (j == st) {
        const int rowg = st * 64 + wave * 16 + fr;
#pragma unroll
        for (int ni = 0; ni < 4; ni++)
#pragma unroll
          for (int r = 0; r < 4; r++) {
            int colg = j * 64 + ni * 16 + fq * 4 + r;
            if (colg > rowg) sc[ni][r] = -1e30f;
          }
      }

      // tile max (raw units): in-register tree + 2 cross-lane steps
      float pmax;
      {
        f32x4 m4 = sc[0];
#pragma unroll
        for (int ni = 1; ni < 4; ni++)
#pragma unroll
          for (int r = 0; r < 4; r++) m4[r] = fmaxf(m4[r], sc[ni][r]);
        pmax = fmaxf(fmaxf(m4[0], m4[1]), fmaxf(m4[2], m4[3]));
        pmax = fmaxf(pmax, __shfl_xor(pmax, 16));
        pmax = fmaxf(pmax, __shfl_xor(pmax, 32));
      }

      // defer-max: rescale only when tile max beats running max by > 8/SCALE
      if (__any(pmax > mr + 90.509668f)) {
        float mnew = fmaxf(mr, pmax);
        float sf = EXP2((mr - mnew) * Cs);
        mr = mnew;
        mC = mr * Cs;
        lp *= sf;
#pragma unroll
        for (int r = 0; r < 4; r++) {
          float sr = __shfl(sf, fq * 4 + r);
#pragma unroll
          for (int n2 = 0; n2 < 8; n2++) ov[n2][r] *= sr;
        }
      }

      // p = exp2(s*Cs - mC); partial-sum; pack bf16; P -> LDS (8 u32 stores)
      {
        char* pb = (char*)Ps + wave * 2048 + fr * 128;
        const int swz = (fr & 7) << 4;
        float lad = 0.f;
#pragma unroll
        for (int ni = 0; ni < 4; ni++) {
          float p0 = EXP2(fmaf(sc[ni][0], Cs, -mC));
          float p1 = EXP2(fmaf(sc[ni][1], Cs, -mC));
          float p2 = EXP2(fmaf(sc[ni][2], Cs, -mC));
          float p3 = EXP2(fmaf(sc[ni][3], Cs, -mC));
          lad += (p0 + p1) + (p2 + p3);
          bf16x2 w0 = {(__bf16)p0, (__bf16)p1};
          bf16x2 w1 = {(__bf16)p2, (__bf16)p3};
          int kb = ni * 32 + fq * 8;
          *(u32*)(pb + (kb ^ swz)) = __builtin_bit_cast(u32, w0);
          *(u32*)(pb + ((kb + 4) ^ swz)) = __builtin_bit_cast(u32, w1);
        }
        lp += lad;
      }

      // O += P V (16 MFMA / wave); ov rows q = fq*4+r, cols d = n2*16+fr
#pragma unroll
      for (int kc = 0; kc < 2; kc++) {
        bf16x8 ap = *(const bf16x8*)((const char*)Ps + wave * 2048 + fr * 128 +
                                     ((kc * 64 + fq * 16) ^ ((fr & 7) << 4)));
#pragma unroll
        for (int n2 = 0; n2 < 8; n2++) {
          int vd = n2 * 16 + fr;
          bf16x8 bv = *(const bf16x8*)((const char*)Vt + vd * 128 +
                                       ((kc * 64 + fq * 16) ^ ((vd & 7) << 4)));
          ov[n2] = __builtin_amdgcn_mfma_f32_16x16x32_bf16(ap, bv, ov[n2], 0, 0, 0);
        }
      }
      __syncthreads();
    }

    // final row-sum reduce + normalize + store (per phase)
    float ls = lp;
    ls += __shfl_xor(ls, 16);
    ls += __shfl_xor(ls, 32);
#pragma unroll
    for (int r = 0; r < 4; r++) {
      float lr = __shfl(ls, fq * 4 + r);
      float inv = 1.0f / lr;
      size_t rowg = (size_t)(b * SEQ + st * 64 + wave * 16 + fq * 4 + r) * HIDDEN + h * HD;
#pragma unroll
      for (int n2 = 0; n2 < 8; n2++)
        Ob[rowg + n2 * 16 + fr] = f2bf(ov[n2][r] * inv);
    }
  }
}

// ---------------- launch --------------------------------------------------
extern "C" void kernel_launch(void* const* d_in, const int* in_sizes, int n_in,
                              void* d_out, int out_size, void* d_ws, size_t ws_size,
                              hipStream_t stream) {
  const float* hidden = (const float*)d_in[0];
  // d_in[1] = attention_mask: exactly the causal mask -> applied analytically
  const int* pos = (const int*)d_in[2];
  const float* Wq = (const float*)d_in[3];
  const float* Wk = (const float*)d_in[4];
  const float* Wv = (const float*)d_in[5];
  const float* Wo = (const float*)d_in[6];
  float* out = (float*)d_out;
  char* ws = (char*)d_ws;

  // workspace layout (bytes), total 120 MiB
  u16* wqkv = (u16*)(ws + 0);         // [4608][3584] bf16
  u16* wob  = (u16*)(ws + 33030144);  // [3584][3584]
  u16* hb   = (u16*)(ws + 58720256);  // [4096][3584] hidden bf16; reused as attn out
  u16* attnb = hb;
  float2* tab = (float2*)(ws + 58720256);  // 1MB sincos table: lives in the dead
                                           // hb window (after QKV gemm, before attn)
  u16* qkv  = (u16*)(ws + 88080384);  // [4096][4608] fused Q|K|V

  cvt_all<<<21504, 256, 0, stream>>>(hidden, Wq, Wk, Wv, Wo, hb, wqkv, wob);

  // fused QKV projection: [4096, 4608] = hb[4096,3584] @ wqkv^T
  gemm256<true><<<288, 512, 0, stream>>>(hb, wqkv, qkv, 4096, QSTR, HIDDEN, 18);

  // RoPE: build table (hb now dead), then apply to Q+K heads
  rope_tab<<<512, 256, 0, stream>>>(tab);
  rope_ip8<<<4096, 256, 0, stream>>>(qkv, pos, tab);

  attn_fwd<<<dim3(16, NH, NB), 256, 0, stream>>>(qkv, attnb);

  gemm256<false><<<224, 512, 0, stream>>>(attnb, wob, out, 4096, HIDDEN, HIDDEN, 14);
}